// Round 4
// baseline (1608.990 us; speedup 1.0000x reference)
//
#include <hip/hip_runtime.h>
#include <hip/hip_bf16.h>

#define H 128
#define IDX_CAP 384  // per-wave staged edge-index capacity (ints); global fallback beyond

using bf16x8  = __attribute__((ext_vector_type(8))) short;  // 8 bf16 = 4 VGPRs
using floatx4 = __attribute__((ext_vector_type(4))) float;

static __device__ __forceinline__ short f2bf(float f) {
  union { float f; unsigned u; } v; v.f = f;
  unsigned r = v.u + 0x7fffu + ((v.u >> 16) & 1u);  // RNE
  return (short)(r >> 16);
}
static __device__ __forceinline__ float bf2f(short s) {
  union { unsigned u; float f; } v; v.u = ((unsigned)(unsigned short)s) << 16;
  return v.f;
}

// ---- degree counts, both relations in one launch ----
__global__ void count_edges2(const int* __restrict__ ev_s, const int* __restrict__ ev_d, int EV,
                             const int* __restrict__ el_s, const int* __restrict__ el_d, int EL,
                             int* __restrict__ cnt, int oV_u, int oV_p, int oL_u, int oL_p) {
  int i = blockIdx.x * blockDim.x + threadIdx.x;
  if (i < EV) {
    atomicAdd(&cnt[oV_u + ev_s[i]], 1);
    atomicAdd(&cnt[oV_p + ev_d[i]], 1);
  } else if (i - EV < EL) {
    int e = i - EV;
    atomicAdd(&cnt[oL_u + el_s[e]], 1);
    atomicAdd(&cnt[oL_p + el_d[e]], 1);
  }
}

// ---- 3-kernel exclusive scan over 4 contiguous count arrays ----
__global__ __launch_bounds__(256) void scan_k1(const int* __restrict__ cnt, int* __restrict__ off,
                                               int* __restrict__ bsums, int4 starts, int4 lens) {
  int a = blockIdx.y;
  int start = ((const int*)&starts)[a];
  int len   = ((const int*)&lens)[a];
  int chunk = blockIdx.x * 1024;
  if (chunk >= len) return;
  const int* in = cnt + start;
  int* out = off + start;
  int tid = threadIdx.x;
  int base = chunk + tid * 4;
  int v[4];
#pragma unroll
  for (int j = 0; j < 4; ++j) v[j] = (base + j < len) ? in[base + j] : 0;
  int s = v[0] + v[1] + v[2] + v[3];
  __shared__ int lds[256];
  lds[tid] = s; __syncthreads();
  for (int o = 1; o < 256; o <<= 1) {
    int t = (tid >= o) ? lds[tid - o] : 0;
    __syncthreads();
    lds[tid] += t;
    __syncthreads();
  }
  int run = lds[tid] - s;  // exclusive prefix of this thread's 4
#pragma unroll
  for (int j = 0; j < 4; ++j) { if (base + j < len) out[base + j] = run; run += v[j]; }
  if (tid == 255) bsums[a * 256 + blockIdx.x] = lds[255];
}

__global__ __launch_bounds__(256) void scan_k2(int* __restrict__ bsums, int4 lens) {
  int a = blockIdx.x;
  int len = ((const int*)&lens)[a];
  int nb = (len + 1023) >> 10;
  int tid = threadIdx.x;
  int s = (tid < nb) ? bsums[a * 256 + tid] : 0;  // guard: slots >= nb are poisoned
  __shared__ int lds[256];
  lds[tid] = s; __syncthreads();
  for (int o = 1; o < 256; o <<= 1) {
    int t = (tid >= o) ? lds[tid - o] : 0;
    __syncthreads();
    lds[tid] += t;
    __syncthreads();
  }
  bsums[a * 256 + tid] = lds[tid] - s;
}

__global__ __launch_bounds__(256) void scan_k3(int* __restrict__ off, const int* __restrict__ bsums,
                                               int4 starts, int4 lens) {
  int a = blockIdx.y;
  int start = ((const int*)&starts)[a];
  int len   = ((const int*)&lens)[a];
  int chunk = blockIdx.x * 1024;
  if (chunk >= len) return;
  int add = bsums[a * 256 + blockIdx.x];
  int* out = off + start;
  int base = chunk + threadIdx.x * 4;
#pragma unroll
  for (int j = 0; j < 4; ++j) if (base + j < len) out[base + j] += add;
}

// ---- CSR fill, both relations (both directions each) in one launch ----
__global__ void fill_csr2(const int* __restrict__ ev_s, const int* __restrict__ ev_d, int EV,
                          const int* __restrict__ el_s, const int* __restrict__ el_d, int EL,
                          const int* __restrict__ off, int* __restrict__ cur,
                          int* __restrict__ sV_p, int* __restrict__ sV_u,
                          int* __restrict__ sL_p, int* __restrict__ sL_u,
                          int oV_p, int oV_u, int oL_p, int oL_u) {
  int i = blockIdx.x * blockDim.x + threadIdx.x;
  if (i < EV) {
    int s = ev_s[i], d = ev_d[i];
    sV_p[off[oV_p + d] + atomicAdd(&cur[oV_p + d], 1)] = s;
    sV_u[off[oV_u + s] + atomicAdd(&cur[oV_u + s], 1)] = d;
  } else if (i - EV < EL) {
    int e = i - EV;
    int s = el_s[e], d = el_d[e];
    sL_p[off[oL_p + d] + atomicAdd(&cur[oL_p + d], 1)] = s;
    sL_u[off[oL_u + s] + atomicAdd(&cur[oL_u + s], 1)] = d;
  }
}

// ---- fp32 -> bf16 streaming convert, both embeddings in one launch ----
__global__ void cvt_bf16_2(const float* __restrict__ inU, short* __restrict__ outU, int nU,
                           const float* __restrict__ inP, short* __restrict__ outP, int nP) {
  int idx = (blockIdx.x * blockDim.x + threadIdx.x) * 4;
  const float* in; short* out;
  if (idx < nU) { in = inU + idx; out = outU + idx; }
  else {
    idx -= nU;
    if (idx >= nP) return;
    in = inP + idx; out = outP + idx;
  }
  float4 v = *(const float4*)in;
  short4 o = { f2bf(v.x), f2bf(v.y), f2bf(v.z), f2bf(v.w) };
  *(short4*)out = o;
}

// ---- weight prep: bf16 convert, combine Wr pair and bias pair per (layer,type).
// Weights written in MFMA B-fragment order:
//   fragment (jt,kk), lane l holds 8 bf16 of W[(jt*16 + (l&15))][kk*32 + (l>>4)*8 + j]
//   stored at ((jt*4+kk)*64 + l)*8 + j
static __device__ __forceinline__ int wswz(int e) {
  int n = e >> 7, k = e & 127;          // W row-major [n][k]
  int jt = n >> 4, r = n & 15;
  int kk = k >> 5, q = (k >> 3) & 3, j = k & 7;
  return (((jt * 4 + kk) * 64 + q * 16 + r) << 3) + j;
}
__global__ void prep_weights(const float* __restrict__ W_l, const float* __restrict__ b_l,
                             const float* __restrict__ W_r,
                             short* __restrict__ Wbf, float* __restrict__ bc) {
  int i = blockIdx.x * blockDim.x + threadIdx.x;
  if (i >= 4 * 16384) return;
  int s = i >> 14, e = i & 16383;
  int l = s >> 1, t = s & 1;
  int rA = t ? 1 : 0, rB = t ? 3 : 2;
  const float* WA = W_l + ((size_t)(l * 4 + rA) << 14);
  const float* WB = W_l + ((size_t)(l * 4 + rB) << 14);
  const float* RA = W_r + ((size_t)(l * 4 + rA) << 14);
  const float* RB = W_r + ((size_t)(l * 4 + rB) << 14);
  short* o = Wbf + (size_t)s * 3 * 16384;
  int d = wswz(e);
  o[d]             = f2bf(WA[e]);
  o[16384 + d]     = f2bf(WB[e]);
  o[2 * 16384 + d] = f2bf(RA[e] + RB[e]);
  if (e < H) bc[s * H + e] = b_l[(l * 4 + rA) * H + e] + b_l[(l * 4 + rB) * H + e];
}

// ---- fully fused SAGE layer: segment-mean + out = mV@WA.T + mL@WB.T + x@WRc.T + b [,ReLU]
// v4: LDS cut to 76 KB -> 2 blocks/CU -> 4 waves/SIMD (r3's 160 KB gave 1 block/CU
// and the short per-row gather chains were latency-exposed at 2 waves/SIMD).
//   64 KB: weight mats 0 (V) and 1 (L) in B-fragment order (staged once, ONE barrier)
//   12 KB: 1.5 KB/wave edge-index buffer (384 ints; covers mean+12sigma of a
//          32-row group; global fallback beyond). Indices ride lgkmcnt.
// Mat 2 (self) B-frags read from GLOBAL: block-uniform addresses, 16 KB set,
// L2-resident on every XCD; only 1/3 of MFMAs, latency covered by 4 waves/SIMD.
// __launch_bounds__(512,4) pins VGPR <= 128 so 2 blocks actually fit.
// A frag: A[m=lane&15][k=quad*8+j]; B frag: B[k][n=lane&15]=W[n][k];
// C/D: col=lane&15, row=quad*4+reg.
__global__ __launch_bounds__(512, 4) void fused_layer(
    const short* __restrict__ xgA, const short* __restrict__ xbA,
    const int* __restrict__ sVA, const int* __restrict__ oVA, const int* __restrict__ cVA,
    const int* __restrict__ sLA, const int* __restrict__ oLA, const int* __restrict__ cLA,
    const short* __restrict__ WAp, const float* __restrict__ biasA,
    float* __restrict__ o32A, short* __restrict__ o16A, int NA, int nbA,
    const short* __restrict__ xgB, const short* __restrict__ xbB,
    const int* __restrict__ sVB, const int* __restrict__ oVB, const int* __restrict__ cVB,
    const int* __restrict__ sLB, const int* __restrict__ oLB, const int* __restrict__ cLB,
    const short* __restrict__ WBp, const float* __restrict__ biasB,
    float* __restrict__ o32B, short* __restrict__ o16B, int NB, int relu) {
  extern __shared__ short smem[];          // 64 KB W (mats 0,1) + 12 KB idx
  short* Wlds = smem;                      // 2 * 16384 shorts
  int* idxLds = (int*)(smem + 2 * 16384);  // 8 waves * 384 ints

  int b = blockIdx.x;
  const short *xg, *xb, *W; const int *sV, *oV, *cV, *sL, *oL, *cL;
  const float* bias; float* out32; short* out16; int N, nbPart, bLoc;
  if (b < nbA) {
    xg = xgA; xb = xbA; sV = sVA; oV = oVA; cV = cVA; sL = sLA; oL = oLA; cL = cLA;
    W = WAp; bias = biasA; out32 = o32A; out16 = o16A; N = NA; nbPart = nbA; bLoc = b;
  } else {
    xg = xgB; xb = xbB; sV = sVB; oV = oVB; cV = cVB; sL = sLB; oL = oLB; cL = cLB;
    W = WBp; bias = biasB; out32 = o32B; out16 = o16B; N = NB;
    nbPart = gridDim.x - nbA; bLoc = b - nbA;
  }

  int tid = threadIdx.x;
  // stage weight mats 0,1 (4096 x 16B chunks), coalesced linear copy
#pragma unroll
  for (int it = 0; it < 8; ++it) {
    int c = it * 512 + tid;
    *(bf16x8*)(Wlds + (size_t)c * 8) = *(const bf16x8*)(W + (size_t)c * 8);
  }
  __syncthreads();  // the ONLY barrier

  int wave = tid >> 6, lane = tid & 63;
  int r = lane & 15, quad = lane >> 4;
  int* myIdx = idxLds + wave * IDX_CAP;

  float bias_r[8];
#pragma unroll
  for (int jt = 0; jt < 8; ++jt) bias_r[jt] = bias[jt * 16 + r];

  int nrgTot = (N + 31) >> 5;
  int wStride = nbPart * 8;
  int wBase = bLoc * 8 + wave;

  floatx4 acc[2][8];

  for (int rg = wBase; rg < nrgTot; rg += wStride) {
    int rowb = rg << 5;

    // ---- xb A-frags: issue early, consumed by MFMA m=2 at the end ----
    bf16x8 afX[2][4];
#pragma unroll
    for (int t = 0; t < 2; ++t) {
      int row = rowb + t * 16 + r;
      row = row < N ? row : N - 1;
      const short* Xr = xb + (size_t)row * H + quad * 8;
#pragma unroll
      for (int kk = 0; kk < 4; ++kk) afX[t][kk] = *(const bf16x8*)(Xr + kk * 32);
    }

    // ---- stage this rowgroup's V and L edge indices into LDS (wave-private) ----
    int rbL = rowb + 31; rbL = rbL < N ? rbL : N - 1;
    int OV0 = oV[rowb];
    int lenV = oV[rbL] + cV[rbL] - OV0;
    int OL0 = oL[rowb];
    int lenL = oL[rbL] + cL[rbL] - OL0;
    int capV = lenV < IDX_CAP ? lenV : IDX_CAP;
    int rem = IDX_CAP - capV;
    int capL = lenL < rem ? lenL : rem;
    for (int k = lane; k < capV; k += 64) myIdx[k] = sV[OV0 + k];
    for (int k = lane; k < capL; k += 64) myIdx[capV + k] = sL[OL0 + k];

#pragma unroll
    for (int t = 0; t < 2; ++t)
#pragma unroll
      for (int j = 0; j < 8; ++j) acc[t][j] = floatx4{0.f, 0.f, 0.f, 0.f};

    bf16x8 afm[2][4];  // mean A-frags for current relation (reused V then L)

    // gather+mean for one relation into afm; depth-2 edge pipeline
    auto gatherRel = [&](const int* __restrict__ offA, const int* __restrict__ cntA,
                         const int* __restrict__ sG, int O0, int base, int cap) {
#pragma unroll
      for (int t = 0; t < 2; ++t) {
        int row = rowb + t * 16 + r;
        int node = row < N ? row : N - 1;
        int o = offA[node], n = cntA[node];
        int lo = o - O0;
        float ag[4][8];
#pragma unroll
        for (int kk = 0; kk < 4; ++kk)
#pragma unroll
          for (int j = 0; j < 8; ++j) ag[kk][j] = 0.f;

        auto gidx = [&](int i) -> int {
          int li = lo + i;
          return (li < cap) ? myIdx[base + li] : sG[o + i];  // LDS fast path (almost always taken)
        };

        bf16x8 pA[4], pB[4];
        if (n > 0) {
          const short* xr = xg + (size_t)gidx(0) * H + quad * 8;
#pragma unroll
          for (int kk = 0; kk < 4; ++kk) pA[kk] = *(const bf16x8*)(xr + kk * 32);
        }
        if (n > 1) {
          const short* xr = xg + (size_t)gidx(1) * H + quad * 8;
#pragma unroll
          for (int kk = 0; kk < 4; ++kk) pB[kk] = *(const bf16x8*)(xr + kk * 32);
        }
        for (int i = 0; i < n; i += 2) {
          bf16x8 nA[4], nB[4];
          if (i + 2 < n) {
            const short* xr = xg + (size_t)gidx(i + 2) * H + quad * 8;
#pragma unroll
            for (int kk = 0; kk < 4; ++kk) nA[kk] = *(const bf16x8*)(xr + kk * 32);
          }
          if (i + 3 < n) {
            const short* xr = xg + (size_t)gidx(i + 3) * H + quad * 8;
#pragma unroll
            for (int kk = 0; kk < 4; ++kk) nB[kk] = *(const bf16x8*)(xr + kk * 32);
          }
#pragma unroll
          for (int kk = 0; kk < 4; ++kk)
#pragma unroll
            for (int j = 0; j < 8; ++j) ag[kk][j] += bf2f(pA[kk][j]);
          if (i + 1 < n) {
#pragma unroll
            for (int kk = 0; kk < 4; ++kk)
#pragma unroll
              for (int j = 0; j < 8; ++j) ag[kk][j] += bf2f(pB[kk][j]);
          }
#pragma unroll
          for (int kk = 0; kk < 4; ++kk) { pA[kk] = nA[kk]; pB[kk] = nB[kk]; }
        }
        float rin = 1.0f / fmaxf((float)n, 1.0f);
#pragma unroll
        for (int kk = 0; kk < 4; ++kk) {
          bf16x8 w;
#pragma unroll
          for (int j = 0; j < 8; ++j) w[j] = f2bf(ag[kk][j] * rin);
          afm[t][kk] = w;
        }
      }
    };

    // MFMA with B-frags from LDS (mats 0,1)
    auto mfmaLds = [&](int m, bf16x8 (&af)[2][4]) {
      const short* Wm = Wlds + m * 16384;
#pragma unroll
      for (int kk = 0; kk < 4; ++kk) {
#pragma unroll
        for (int jt = 0; jt < 8; ++jt) {
          bf16x8 bfR = *(const bf16x8*)(Wm + (size_t)((jt * 4 + kk) * 64 + lane) * 8);
          acc[0][jt] = __builtin_amdgcn_mfma_f32_16x16x32_bf16(af[0][kk], bfR, acc[0][jt], 0, 0, 0);
          acc[1][jt] = __builtin_amdgcn_mfma_f32_16x16x32_bf16(af[1][kk], bfR, acc[1][jt], 0, 0, 0);
        }
      }
    };

    // MFMA with B-frags from global (mat 2, self): uniform addresses, L2-hot
    auto mfmaGlb = [&](bf16x8 (&af)[2][4]) {
      const short* Wm = W + 2 * 16384;
#pragma unroll
      for (int kk = 0; kk < 4; ++kk) {
#pragma unroll
        for (int jt = 0; jt < 8; ++jt) {
          bf16x8 bfR = *(const bf16x8*)(Wm + (size_t)((jt * 4 + kk) * 64 + lane) * 8);
          acc[0][jt] = __builtin_amdgcn_mfma_f32_16x16x32_bf16(af[0][kk], bfR, acc[0][jt], 0, 0, 0);
          acc[1][jt] = __builtin_amdgcn_mfma_f32_16x16x32_bf16(af[1][kk], bfR, acc[1][jt], 0, 0, 0);
        }
      }
    };

    gatherRel(oV, cV, sV, OV0, 0, capV);     // viewed means -> afm
    mfmaLds(0, afm);
    gatherRel(oL, cL, sL, OL0, capV, capL);  // liked means -> afm
    mfmaLds(1, afm);
    mfmaGlb(afX);                            // self transform

    // ---- epilogue ----
#pragma unroll
    for (int t = 0; t < 2; ++t) {
#pragma unroll
      for (int jt = 0; jt < 8; ++jt) {
        int ocol = jt * 16 + r;
        float bv = bias_r[jt];
#pragma unroll
        for (int g = 0; g < 4; ++g) {
          int orow = rowb + t * 16 + quad * 4 + g;
          if (orow < N) {
            float v = acc[t][jt][g] + bv;
            if (relu) v = fmaxf(v, 0.f);
            if (out32) out32[(size_t)orow * H + ocol] = v;
            else       out16[(size_t)orow * H + ocol] = f2bf(v);
          }
        }
      }
    }
  }
}

extern "C" void kernel_launch(void* const* d_in, const int* in_sizes, int n_in,
                              void* d_out, int out_size, void* d_ws, size_t ws_size,
                              hipStream_t stream) {
  const float* emb_user = (const float*)d_in[0];
  const float* emb_post = (const float*)d_in[1];
  const float* W_l = (const float*)d_in[2];
  const float* b_l = (const float*)d_in[3];
  const float* W_r = (const float*)d_in[4];
  const int* ev_s = (const int*)d_in[5];
  const int* ev_d = (const int*)d_in[6];
  const int* el_s = (const int*)d_in[7];
  const int* el_d = (const int*)d_in[8];

  const int NU = in_sizes[0] / H;
  const int NP = in_sizes[1] / H;
  const int EV = in_sizes[5];
  const int EL = in_sizes[7];
  const int T = 2 * NP + 2 * NU;
  const size_t NUH = (size_t)NU * H, NPH = (size_t)NP * H;

  // workspace carve (256B-aligned bumps)
  char* p = (char*)d_ws;
  auto alloc = [&](size_t bytes) -> void* {
    void* q = (void*)p; p += (bytes + 255) & ~(size_t)255; return q;
  };
  int*   cnt   = (int*)alloc((size_t)T * 4);
  int*   cur   = (int*)alloc((size_t)T * 4);
  int*   off   = (int*)alloc((size_t)T * 4);
  int*   bsums = (int*)alloc(4 * 256 * 4);
  int*   sV_p  = (int*)alloc((size_t)EV * 4);
  int*   sV_u  = (int*)alloc((size_t)EV * 4);
  int*   sL_p  = (int*)alloc((size_t)EL * 4);
  int*   sL_u  = (int*)alloc((size_t)EL * 4);
  short* Wbf   = (short*)alloc((size_t)4 * 3 * 16384 * 2);
  float* bc    = (float*)alloc(4 * H * 4);
  short* xbf_u  = (short*)alloc(NUH * 2);
  short* xbf_p  = (short*)alloc(NPH * 2);
  short* xbf1_u = (short*)alloc(NUH * 2);
  short* xbf1_p = (short*)alloc(NPH * 2);

  float* out_u_final = (float*)d_out;
  float* out_p_final = (float*)d_out + NUH;

  // count-array index order: {V_p:0, L_p:NP, V_u:2NP, L_u:2NP+NU}
  const int oV_p = 0, oL_p = NP, oV_u = 2 * NP, oL_u = 2 * NP + NU;

  hipMemsetAsync(cnt, 0, (size_t)T * 4, stream);
  hipMemsetAsync(cur, 0, (size_t)T * 4, stream);
  count_edges2<<<(EV + EL + 255) / 256, 256, 0, stream>>>(
      ev_s, ev_d, EV, el_s, el_d, EL, cnt, oV_u, oV_p, oL_u, oL_p);

  int4 starts = { oV_p, oL_p, oV_u, oL_u };
  int4 lens   = { NP, NP, NU, NU };
  int maxb = ((NP > NU ? NP : NU) + 1023) / 1024;
  dim3 gscan(maxb, 4, 1);
  scan_k1<<<gscan, 256, 0, stream>>>(cnt, off, bsums, starts, lens);
  scan_k2<<<4, 256, 0, stream>>>(bsums, lens);
  scan_k3<<<gscan, 256, 0, stream>>>(off, bsums, starts, lens);

  fill_csr2<<<(EV + EL + 255) / 256, 256, 0, stream>>>(
      ev_s, ev_d, EV, el_s, el_d, EL, off, cur,
      sV_p, sV_u, sL_p, sL_u, oV_p, oV_u, oL_p, oL_u);

  cvt_bf16_2<<<((int)((NUH + NPH) / 4) + 255) / 256, 256, 0, stream>>>(
      emb_user, xbf_u, (int)NUH, emb_post, xbf_p, (int)NPH);
  prep_weights<<<(4 * 16384 + 255) / 256, 256, 0, stream>>>(W_l, b_l, W_r, Wbf, bc);

  // dynamic LDS: 64 KB weights + 12 KB idx = 77824 B (2 blocks/CU)
  const int ldsBytes = 2 * 16384 * 2 + 8 * IDX_CAP * 4;
  hipFuncSetAttribute((const void*)fused_layer, hipFuncAttributeMaxDynamicSharedMemorySize,
                      ldsBytes);

  // block split: both parts have (EV+EL) gather-edges; fixed per-row work ~ 3 units
  long long wP = (long long)(EV + EL) + 3LL * NP;
  long long wU = (long long)(EV + EL) + 3LL * NU;
  int nbP = (int)((256LL * wP) / (wP + wU));
  if (nbP < 1) nbP = 1;
  if (nbP > 255) nbP = 255;

  for (int l = 0; l < 2; ++l) {
    const short* xu = l ? xbf1_u : xbf_u;
    const short* xp = l ? xbf1_p : xbf_p;
    const short* Wpost = Wbf + (size_t)(l * 2 + 0) * 3 * 16384;
    const short* Wuser = Wbf + (size_t)(l * 2 + 1) * 3 * 16384;
    const float* bpost = bc + (l * 2 + 0) * H;
    const float* buser = bc + (l * 2 + 1) * H;

    fused_layer<<<256, 512, ldsBytes, stream>>>(
        // part A: posts (gather user features into post rows)
        xu, xp, sV_p, off + oV_p, cnt + oV_p, sL_p, off + oL_p, cnt + oL_p,
        Wpost, bpost, l ? out_p_final : nullptr, l ? nullptr : xbf1_p, NP, nbP,
        // part B: users (gather post features into user rows)
        xp, xu, sV_u, off + oV_u, cnt + oV_u, sL_u, off + oL_u, cnt + oL_u,
        Wuser, buser, l ? out_u_final : nullptr, l ? nullptr : xbf1_u, NU, l == 0);
  }
}

// Round 5
// 833.163 us; speedup vs baseline: 1.9312x; 1.9312x over previous
//
#include <hip/hip_runtime.h>
#include <hip/hip_bf16.h>

#define H 128

using bf16x8  = __attribute__((ext_vector_type(8))) short;  // 8 bf16 = 4 VGPRs
using floatx4 = __attribute__((ext_vector_type(4))) float;

static __device__ __forceinline__ short f2bf(float f) {
  union { float f; unsigned u; } v; v.f = f;
  unsigned r = v.u + 0x7fffu + ((v.u >> 16) & 1u);  // RNE
  return (short)(r >> 16);
}
static __device__ __forceinline__ float bf2f(short s) {
  union { unsigned u; float f; } v; v.u = ((unsigned)(unsigned short)s) << 16;
  return v.f;
}

// ---- degree counts, both relations in one launch ----
__global__ void count_edges2(const int* __restrict__ ev_s, const int* __restrict__ ev_d, int EV,
                             const int* __restrict__ el_s, const int* __restrict__ el_d, int EL,
                             int* __restrict__ cnt, int oV_u, int oV_p, int oL_u, int oL_p) {
  int i = blockIdx.x * blockDim.x + threadIdx.x;
  if (i < EV) {
    atomicAdd(&cnt[oV_u + ev_s[i]], 1);
    atomicAdd(&cnt[oV_p + ev_d[i]], 1);
  } else if (i - EV < EL) {
    int e = i - EV;
    atomicAdd(&cnt[oL_u + el_s[e]], 1);
    atomicAdd(&cnt[oL_p + el_d[e]], 1);
  }
}

// ---- 3-kernel exclusive scan over 4 contiguous count arrays ----
__global__ __launch_bounds__(256) void scan_k1(const int* __restrict__ cnt, int* __restrict__ off,
                                               int* __restrict__ bsums, int4 starts, int4 lens) {
  int a = blockIdx.y;
  int start = ((const int*)&starts)[a];
  int len   = ((const int*)&lens)[a];
  int chunk = blockIdx.x * 1024;
  if (chunk >= len) return;
  const int* in = cnt + start;
  int* out = off + start;
  int tid = threadIdx.x;
  int base = chunk + tid * 4;
  int v[4];
#pragma unroll
  for (int j = 0; j < 4; ++j) v[j] = (base + j < len) ? in[base + j] : 0;
  int s = v[0] + v[1] + v[2] + v[3];
  __shared__ int lds[256];
  lds[tid] = s; __syncthreads();
  for (int o = 1; o < 256; o <<= 1) {
    int t = (tid >= o) ? lds[tid - o] : 0;
    __syncthreads();
    lds[tid] += t;
    __syncthreads();
  }
  int run = lds[tid] - s;  // exclusive prefix of this thread's 4
#pragma unroll
  for (int j = 0; j < 4; ++j) { if (base + j < len) out[base + j] = run; run += v[j]; }
  if (tid == 255) bsums[a * 256 + blockIdx.x] = lds[255];
}

__global__ __launch_bounds__(256) void scan_k2(int* __restrict__ bsums, int4 lens) {
  int a = blockIdx.x;
  int len = ((const int*)&lens)[a];
  int nb = (len + 1023) >> 10;
  int tid = threadIdx.x;
  int s = (tid < nb) ? bsums[a * 256 + tid] : 0;  // guard: slots >= nb are poisoned
  __shared__ int lds[256];
  lds[tid] = s; __syncthreads();
  for (int o = 1; o < 256; o <<= 1) {
    int t = (tid >= o) ? lds[tid - o] : 0;
    __syncthreads();
    lds[tid] += t;
    __syncthreads();
  }
  bsums[a * 256 + tid] = lds[tid] - s;
}

__global__ __launch_bounds__(256) void scan_k3(int* __restrict__ off, const int* __restrict__ bsums,
                                               int4 starts, int4 lens) {
  int a = blockIdx.y;
  int start = ((const int*)&starts)[a];
  int len   = ((const int*)&lens)[a];
  int chunk = blockIdx.x * 1024;
  if (chunk >= len) return;
  int add = bsums[a * 256 + blockIdx.x];
  int* out = off + start;
  int base = chunk + threadIdx.x * 4;
#pragma unroll
  for (int j = 0; j < 4; ++j) if (base + j < len) out[base + j] += add;
}

// ---- CSR fill, both relations (both directions each) in one launch ----
__global__ void fill_csr2(const int* __restrict__ ev_s, const int* __restrict__ ev_d, int EV,
                          const int* __restrict__ el_s, const int* __restrict__ el_d, int EL,
                          const int* __restrict__ off, int* __restrict__ cur,
                          int* __restrict__ sV_p, int* __restrict__ sV_u,
                          int* __restrict__ sL_p, int* __restrict__ sL_u,
                          int oV_p, int oV_u, int oL_p, int oL_u) {
  int i = blockIdx.x * blockDim.x + threadIdx.x;
  if (i < EV) {
    int s = ev_s[i], d = ev_d[i];
    sV_p[off[oV_p + d] + atomicAdd(&cur[oV_p + d], 1)] = s;
    sV_u[off[oV_u + s] + atomicAdd(&cur[oV_u + s], 1)] = d;
  } else if (i - EV < EL) {
    int e = i - EV;
    int s = el_s[e], d = el_d[e];
    sL_p[off[oL_p + d] + atomicAdd(&cur[oL_p + d], 1)] = s;
    sL_u[off[oL_u + s] + atomicAdd(&cur[oL_u + s], 1)] = d;
  }
}

// ---- fp32 -> bf16 streaming convert, both embeddings in one launch ----
__global__ void cvt_bf16_2(const float* __restrict__ inU, short* __restrict__ outU, int nU,
                           const float* __restrict__ inP, short* __restrict__ outP, int nP) {
  int idx = (blockIdx.x * blockDim.x + threadIdx.x) * 4;
  const float* in; short* out;
  if (idx < nU) { in = inU + idx; out = outU + idx; }
  else {
    idx -= nU;
    if (idx >= nP) return;
    in = inP + idx; out = outP + idx;
  }
  float4 v = *(const float4*)in;
  short4 o = { f2bf(v.x), f2bf(v.y), f2bf(v.z), f2bf(v.w) };
  *(short4*)out = o;
}

// ---- weight prep: bf16 convert, combine Wr pair and bias pair per (layer,type).
// Weights written in MFMA B-fragment order:
//   fragment (jt,kk), lane l holds 8 bf16 of W[(jt*16 + (l&15))][kk*32 + (l>>4)*8 + j]
//   stored at ((jt*4+kk)*64 + l)*8 + j
static __device__ __forceinline__ int wswz(int e) {
  int n = e >> 7, k = e & 127;          // W row-major [n][k]
  int jt = n >> 4, r = n & 15;
  int kk = k >> 5, q = (k >> 3) & 3, j = k & 7;
  return (((jt * 4 + kk) * 64 + q * 16 + r) << 3) + j;
}
__global__ void prep_weights(const float* __restrict__ W_l, const float* __restrict__ b_l,
                             const float* __restrict__ W_r,
                             short* __restrict__ Wbf, float* __restrict__ bc) {
  int i = blockIdx.x * blockDim.x + threadIdx.x;
  if (i >= 4 * 16384) return;
  int s = i >> 14, e = i & 16383;
  int l = s >> 1, t = s & 1;
  int rA = t ? 1 : 0, rB = t ? 3 : 2;
  const float* WA = W_l + ((size_t)(l * 4 + rA) << 14);
  const float* WB = W_l + ((size_t)(l * 4 + rB) << 14);
  const float* RA = W_r + ((size_t)(l * 4 + rA) << 14);
  const float* RB = W_r + ((size_t)(l * 4 + rB) << 14);
  short* o = Wbf + (size_t)s * 3 * 16384;
  int d = wswz(e);
  o[d]             = f2bf(WA[e]);
  o[16384 + d]     = f2bf(WB[e]);
  o[2 * 16384 + d] = f2bf(RA[e] + RB[e]);
  if (e < H) bc[s * H + e] = b_l[(l * 4 + rA) * H + e] + b_l[(l * 4 + rB) * H + e];
}

// ---- fused segment-mean for BOTH parts (posts + users) in one launch.
// 16 lanes per node, bf16x8 per lane, fp32 accum. x4-unrolled gathers (4 in
// flight). v5: (a) nontemporal stores for mV/mL -- the 153.6 MB write-once
// stream no longer thrashes L3 against the 77 MB gather working set;
// (b) L-relation's first two feature gathers are issued BEFORE V's finalize
// drain, so the V->L serialization is hidden (in-order vmcnt completes them
// for free while waiting on V's last gather).
__global__ __launch_bounds__(256) void aggregate2(
    const bf16x8* __restrict__ xA,
    const int* __restrict__ sVA, const int* __restrict__ oVA, const int* __restrict__ cVA,
    const int* __restrict__ sLA, const int* __restrict__ oLA, const int* __restrict__ cLA,
    bf16x8* __restrict__ mVA, bf16x8* __restrict__ mLA, int NA, int nbA,
    const bf16x8* __restrict__ xB,
    const int* __restrict__ sVB, const int* __restrict__ oVB, const int* __restrict__ cVB,
    const int* __restrict__ sLB, const int* __restrict__ oLB, const int* __restrict__ cLB,
    bf16x8* __restrict__ mVB, bf16x8* __restrict__ mLB, int NB) {
  int b = blockIdx.x;
  const bf16x8* x; const int *sV, *oV, *cV, *sL, *oL, *cL;
  bf16x8 *mV, *mL; int N, t0;
  if (b < nbA) {
    x = xA; sV = sVA; oV = oVA; cV = cVA; sL = sLA; oL = oLA; cL = cLA;
    mV = mVA; mL = mLA; N = NA; t0 = b * 256;
  } else {
    x = xB; sV = sVB; oV = oVB; cV = cVB; sL = sLB; oL = oLB; cL = cLB;
    mV = mVB; mL = mLB; N = NB; t0 = (b - nbA) * 256;
  }
  int t = t0 + threadIdx.x;
  int node = t >> 4, c = t & 15;
  if (node >= N) return;

  int oVn = oV[node], nV = cV[node];
  int oLn = oL[node], nL = cL[node];

  // prefetch L's first two gathers so they overlap V's chain
  bf16x8 pAL{}, pBL{};
  if (nL > 0) pAL = x[(size_t)sL[oLn] * 16 + c];
  if (nL > 1) pBL = x[(size_t)sL[oLn + 1] * 16 + c];

  float acc[8];
  {  // V relation
#pragma unroll
    for (int j = 0; j < 8; ++j) acc[j] = 0.f;
    int i = 0;
    for (; i + 4 <= nV; i += 4) {
      int s0 = sV[oVn + i], s1 = sV[oVn + i + 1], s2 = sV[oVn + i + 2], s3 = sV[oVn + i + 3];
      bf16x8 v0 = x[(size_t)s0 * 16 + c];
      bf16x8 v1 = x[(size_t)s1 * 16 + c];
      bf16x8 v2 = x[(size_t)s2 * 16 + c];
      bf16x8 v3 = x[(size_t)s3 * 16 + c];
#pragma unroll
      for (int j = 0; j < 8; ++j) acc[j] += bf2f(v0[j]);
#pragma unroll
      for (int j = 0; j < 8; ++j) acc[j] += bf2f(v1[j]);
#pragma unroll
      for (int j = 0; j < 8; ++j) acc[j] += bf2f(v2[j]);
#pragma unroll
      for (int j = 0; j < 8; ++j) acc[j] += bf2f(v3[j]);
    }
    for (; i < nV; ++i) {
      bf16x8 v = x[(size_t)sV[oVn + i] * 16 + c];
#pragma unroll
      for (int j = 0; j < 8; ++j) acc[j] += bf2f(v[j]);
    }
    float rin = 1.0f / fmaxf((float)nV, 1.0f);
    bf16x8 w;
#pragma unroll
    for (int j = 0; j < 8; ++j) w[j] = f2bf(acc[j] * rin);
    __builtin_nontemporal_store(w, &mV[(size_t)node * 16 + c]);
  }
  {  // L relation (first two already in pAL/pBL)
#pragma unroll
    for (int j = 0; j < 8; ++j) acc[j] = 0.f;
    if (nL > 0) {
#pragma unroll
      for (int j = 0; j < 8; ++j) acc[j] += bf2f(pAL[j]);
    }
    if (nL > 1) {
#pragma unroll
      for (int j = 0; j < 8; ++j) acc[j] += bf2f(pBL[j]);
    }
    int i = 2;
    for (; i + 4 <= nL; i += 4) {
      int s0 = sL[oLn + i], s1 = sL[oLn + i + 1], s2 = sL[oLn + i + 2], s3 = sL[oLn + i + 3];
      bf16x8 v0 = x[(size_t)s0 * 16 + c];
      bf16x8 v1 = x[(size_t)s1 * 16 + c];
      bf16x8 v2 = x[(size_t)s2 * 16 + c];
      bf16x8 v3 = x[(size_t)s3 * 16 + c];
#pragma unroll
      for (int j = 0; j < 8; ++j) acc[j] += bf2f(v0[j]);
#pragma unroll
      for (int j = 0; j < 8; ++j) acc[j] += bf2f(v1[j]);
#pragma unroll
      for (int j = 0; j < 8; ++j) acc[j] += bf2f(v2[j]);
#pragma unroll
      for (int j = 0; j < 8; ++j) acc[j] += bf2f(v3[j]);
    }
    for (; i < nL; ++i) {
      bf16x8 v = x[(size_t)sL[oLn + i] * 16 + c];
#pragma unroll
      for (int j = 0; j < 8; ++j) acc[j] += bf2f(v[j]);
    }
    float rin = 1.0f / fmaxf((float)nL, 1.0f);
    bf16x8 w;
#pragma unroll
    for (int j = 0; j < 8; ++j) w[j] = f2bf(acc[j] * rin);
    __builtin_nontemporal_store(w, &mL[(size_t)node * 16 + c]);
  }
}

// ---- fused SAGE transform v5: out = mV@WA.T + mL@WB.T + x@WRc.T + b [, ReLU]
// Both parts in ONE launch, 512 blocks (2/CU target) x 512 threads, 64 KB LDS
// (weight mats 0,1 only; mat 2 B-frags from global -- block-uniform 16 KB set,
// L1/L2-hot after first rowgroup). One __syncthreads. A-pipeline is 2-buffer
// with a 2-rowgroup-unrolled static rotation (X/Y), keeping VGPR ~120 <= 128
// so 2 blocks/CU co-reside -> 4 waves/SIMD. A streams (mV/mL/xb, read-once)
// use nontemporal loads; final f32 output uses nontemporal stores.
// A frag: A[m=lane&15][k=quad*8+j]; B frag: B[k][n=lane&15]=W[n][k];
// C/D: col=lane&15, row=quad*4+reg.
__global__ __launch_bounds__(512, 2) void fused_gemm2(
    const short* __restrict__ mVA, const short* __restrict__ mLA, const short* __restrict__ xbA,
    const short* __restrict__ WAp, const float* __restrict__ biasA,
    float* __restrict__ o32A, short* __restrict__ o16A, int NA, int nbA,
    const short* __restrict__ mVB, const short* __restrict__ mLB, const short* __restrict__ xbB,
    const short* __restrict__ WBp, const float* __restrict__ biasB,
    float* __restrict__ o32B, short* __restrict__ o16B, int NB, int relu) {
  extern __shared__ short Wlds[];  // 2 * 16384 shorts = 64 KB (mats 0,1)
  int b = blockIdx.x;
  const short *mV, *mL, *xb, *W; const float* bias;
  float* out32; short* out16; int N, nbPart, bLoc;
  if (b < nbA) {
    mV = mVA; mL = mLA; xb = xbA; W = WAp; bias = biasA;
    out32 = o32A; out16 = o16A; N = NA; nbPart = nbA; bLoc = b;
  } else {
    mV = mVB; mL = mLB; xb = xbB; W = WBp; bias = biasB;
    out32 = o32B; out16 = o16B; N = NB; nbPart = gridDim.x - nbA; bLoc = b - nbA;
  }

  int tid = threadIdx.x;
  // stage mats 0,1 (4096 x 16B chunks), coalesced linear copy
#pragma unroll
  for (int it = 0; it < 8; ++it) {
    int cch = it * 512 + tid;
    *(bf16x8*)(Wlds + (size_t)cch * 8) = *(const bf16x8*)(W + (size_t)cch * 8);
  }
  __syncthreads();  // the ONLY barrier

  int wave = tid >> 6, lane = tid & 63;
  int r = lane & 15, quad = lane >> 4;

  float bias_r[8];
#pragma unroll
  for (int jt = 0; jt < 8; ++jt) bias_r[jt] = bias[jt * 16 + r];

  int nrgTot = (N + 31) >> 5;
  int wStride = nbPart * 8;
  int wBase = bLoc * 8 + wave;
  int nrgW = (wBase < nrgTot) ? (nrgTot - wBase + wStride - 1) / wStride : 0;

  floatx4 acc[2][8];
#pragma unroll
  for (int t = 0; t < 2; ++t)
#pragma unroll
    for (int j = 0; j < 8; ++j) acc[t][j] = floatx4{0.f, 0.f, 0.f, 0.f};

  auto issueA = [&](int j, int m, bf16x8 (&buf)[2][4]) {
    if (j >= nrgW) return;  // wave-uniform
    int rowb = (wBase + j * wStride) << 5;
    const short* X = (m == 0) ? mV : (m == 1) ? mL : xb;
#pragma unroll
    for (int t = 0; t < 2; ++t) {
      int row = rowb + t * 16 + r;
      row = row < N ? row : N - 1;
      const short* Xr = X + (size_t)row * H + quad * 8;
#pragma unroll
      for (int kk = 0; kk < 4; ++kk)
        buf[t][kk] = __builtin_nontemporal_load((const bf16x8*)(Xr + kk * 32));
    }
  };

  auto mfmaLds = [&](int m, bf16x8 (&af)[2][4]) {
    const short* Wm = Wlds + m * 16384;
#pragma unroll
    for (int kk = 0; kk < 4; ++kk) {
#pragma unroll
      for (int jt = 0; jt < 8; ++jt) {
        bf16x8 bfR = *(const bf16x8*)(Wm + (size_t)((jt * 4 + kk) * 64 + lane) * 8);
        acc[0][jt] = __builtin_amdgcn_mfma_f32_16x16x32_bf16(af[0][kk], bfR, acc[0][jt], 0, 0, 0);
        acc[1][jt] = __builtin_amdgcn_mfma_f32_16x16x32_bf16(af[1][kk], bfR, acc[1][jt], 0, 0, 0);
      }
    }
  };

  auto mfmaGlb = [&](bf16x8 (&af)[2][4]) {
    const short* Wm = W + 2 * 16384;  // global, block-uniform, L1/L2-hot
#pragma unroll
    for (int kk = 0; kk < 4; ++kk) {
#pragma unroll
      for (int jt = 0; jt < 8; ++jt) {
        bf16x8 bfR = *(const bf16x8*)(Wm + (size_t)((jt * 4 + kk) * 64 + lane) * 8);
        acc[0][jt] = __builtin_amdgcn_mfma_f32_16x16x32_bf16(af[0][kk], bfR, acc[0][jt], 0, 0, 0);
        acc[1][jt] = __builtin_amdgcn_mfma_f32_16x16x32_bf16(af[1][kk], bfR, acc[1][jt], 0, 0, 0);
      }
    }
  };

  auto epi = [&](int j) {
    int rowb = (wBase + j * wStride) << 5;
#pragma unroll
    for (int t = 0; t < 2; ++t) {
#pragma unroll
      for (int jt = 0; jt < 8; ++jt) {
        int ocol = jt * 16 + r;
        float bv = bias_r[jt];
#pragma unroll
        for (int g = 0; g < 4; ++g) {
          int orow = rowb + t * 16 + quad * 4 + g;
          if (orow < N) {
            float v = acc[t][jt][g] + bv;
            if (relu) v = fmaxf(v, 0.f);
            if (out32) __builtin_nontemporal_store(v, &out32[(size_t)orow * H + ocol]);
            else       out16[(size_t)orow * H + ocol] = f2bf(v);
          }
        }
        acc[t][jt] = floatx4{0.f, 0.f, 0.f, 0.f};
      }
    }
  };

  // 2-buffer A pipeline, 2-rowgroup unrolled static rotation.
  // Invariant at loop top: X = (j, mat0), Y = (j, mat1).
  bf16x8 X[2][4], Y[2][4];
  int j = 0;
  issueA(0, 0, X);
  issueA(0, 1, Y);
  for (; j + 2 <= nrgW; j += 2) {
    mfmaLds(0, X); issueA(j, 2, X);
    mfmaLds(1, Y); issueA(j + 1, 0, Y);
    mfmaGlb(X);    issueA(j + 1, 1, X);
    epi(j);
    mfmaLds(0, Y); issueA(j + 1, 2, Y);
    mfmaLds(1, X); issueA(j + 2, 0, X);
    mfmaGlb(Y);    issueA(j + 2, 1, Y);
    epi(j + 1);
  }
  if (j < nrgW) {  // odd tail: X=(j,0), Y=(j,1)
    mfmaLds(0, X); issueA(j, 2, X);
    mfmaLds(1, Y);
    mfmaGlb(X);
    epi(j);
  }
}

extern "C" void kernel_launch(void* const* d_in, const int* in_sizes, int n_in,
                              void* d_out, int out_size, void* d_ws, size_t ws_size,
                              hipStream_t stream) {
  const float* emb_user = (const float*)d_in[0];
  const float* emb_post = (const float*)d_in[1];
  const float* W_l = (const float*)d_in[2];
  const float* b_l = (const float*)d_in[3];
  const float* W_r = (const float*)d_in[4];
  const int* ev_s = (const int*)d_in[5];
  const int* ev_d = (const int*)d_in[6];
  const int* el_s = (const int*)d_in[7];
  const int* el_d = (const int*)d_in[8];

  const int NU = in_sizes[0] / H;
  const int NP = in_sizes[1] / H;
  const int EV = in_sizes[5];
  const int EL = in_sizes[7];
  const int T = 2 * NP + 2 * NU;
  const size_t NUH = (size_t)NU * H, NPH = (size_t)NP * H;

  // workspace carve (256B-aligned bumps)
  char* p = (char*)d_ws;
  auto alloc = [&](size_t bytes) -> void* {
    void* q = (void*)p; p += (bytes + 255) & ~(size_t)255; return q;
  };
  int*   cnt   = (int*)alloc((size_t)T * 4);
  int*   cur   = (int*)alloc((size_t)T * 4);
  int*   off   = (int*)alloc((size_t)T * 4);
  int*   bsums = (int*)alloc(4 * 256 * 4);
  int*   sV_p  = (int*)alloc((size_t)EV * 4);
  int*   sV_u  = (int*)alloc((size_t)EV * 4);
  int*   sL_p  = (int*)alloc((size_t)EL * 4);
  int*   sL_u  = (int*)alloc((size_t)EL * 4);
  short* Wbf   = (short*)alloc((size_t)4 * 3 * 16384 * 2);
  float* bc    = (float*)alloc(4 * H * 4);
  short* xbf_u  = (short*)alloc(NUH * 2);
  short* xbf_p  = (short*)alloc(NPH * 2);
  short* xbf1_u = (short*)alloc(NUH * 2);
  short* xbf1_p = (short*)alloc(NPH * 2);
  short* mVp    = (short*)alloc(NPH * 2);
  short* mLp    = (short*)alloc(NPH * 2);
  short* mVu    = (short*)alloc(NUH * 2);
  short* mLu    = (short*)alloc(NUH * 2);

  float* out_u_final = (float*)d_out;
  float* out_p_final = (float*)d_out + NUH;

  // count-array index order: {V_p:0, L_p:NP, V_u:2NP, L_u:2NP+NU}
  const int oV_p = 0, oL_p = NP, oV_u = 2 * NP, oL_u = 2 * NP + NU;

  hipMemsetAsync(cnt, 0, (size_t)T * 4, stream);
  hipMemsetAsync(cur, 0, (size_t)T * 4, stream);
  count_edges2<<<(EV + EL + 255) / 256, 256, 0, stream>>>(
      ev_s, ev_d, EV, el_s, el_d, EL, cnt, oV_u, oV_p, oL_u, oL_p);

  int4 starts = { oV_p, oL_p, oV_u, oL_u };
  int4 lens   = { NP, NP, NU, NU };
  int maxb = ((NP > NU ? NP : NU) + 1023) / 1024;
  dim3 gscan(maxb, 4, 1);
  scan_k1<<<gscan, 256, 0, stream>>>(cnt, off, bsums, starts, lens);
  scan_k2<<<4, 256, 0, stream>>>(bsums, lens);
  scan_k3<<<gscan, 256, 0, stream>>>(off, bsums, starts, lens);

  fill_csr2<<<(EV + EL + 255) / 256, 256, 0, stream>>>(
      ev_s, ev_d, EV, el_s, el_d, EL, off, cur,
      sV_p, sV_u, sL_p, sL_u, oV_p, oV_u, oL_p, oL_u);

  cvt_bf16_2<<<((int)((NUH + NPH) / 4) + 255) / 256, 256, 0, stream>>>(
      emb_user, xbf_u, (int)NUH, emb_post, xbf_p, (int)NPH);
  prep_weights<<<(4 * 16384 + 255) / 256, 256, 0, stream>>>(W_l, b_l, W_r, Wbf, bc);

  // dynamic LDS for gemm: 64 KB (2 weight mats)
  const int ldsBytes = 2 * 16384 * 2;
  hipFuncSetAttribute((const void*)fused_gemm2, hipFuncAttributeMaxDynamicSharedMemorySize,
                      ldsBytes);

  // aggregate grid split (16 nodes per 256-thread block)
  int nbAggP = (NP + 15) / 16;
  int nbAggU = (NU + 15) / 16;

  // gemm grid: 512 blocks (2/CU), split proportional to rows
  const int GB = 512;
  int nbP = (int)(((long long)GB * NP) / ((long long)NP + NU));
  if (nbP < 1) nbP = 1;
  if (nbP > GB - 1) nbP = GB - 1;

  for (int l = 0; l < 2; ++l) {
    const short* xu = l ? xbf1_u : xbf_u;
    const short* xp = l ? xbf1_p : xbf_p;
    const short* Wpost = Wbf + (size_t)(l * 2 + 0) * 3 * 16384;
    const short* Wuser = Wbf + (size_t)(l * 2 + 1) * 3 * 16384;
    const float* bpost = bc + (l * 2 + 0) * H;
    const float* buser = bc + (l * 2 + 1) * H;

    // both aggregations (posts from users, users from posts) in one launch
    aggregate2<<<nbAggP + nbAggU, 256, 0, stream>>>(
        (const bf16x8*)xu,
        sV_p, off + oV_p, cnt + oV_p,
        sL_p, off + oL_p, cnt + oL_p,
        (bf16x8*)mVp, (bf16x8*)mLp, NP, nbAggP,
        (const bf16x8*)xp,
        sV_u, off + oV_u, cnt + oV_u,
        sL_u, off + oL_u, cnt + oL_u,
        (bf16x8*)mVu, (bf16x8*)mLu, NU);

    // both transforms in one launch
    fused_gemm2<<<GB, 512, ldsBytes, stream>>>(
        mVp, mLp, xp, Wpost, bpost,
        l ? out_p_final : nullptr, l ? nullptr : xbf1_p, NP, nbP,
        mVu, mLu, xu, Wuser, buser,
        l ? out_u_final : nullptr, l ? nullptr : xbf1_u, NU, l == 0);
  }
}

// Round 6
// 730.597 us; speedup vs baseline: 2.2023x; 1.1404x over previous
//
#include <hip/hip_runtime.h>
#include <hip/hip_bf16.h>

#define H 128

using bf16x8  = __attribute__((ext_vector_type(8))) short;  // 8 bf16 = 4 VGPRs
using floatx4 = __attribute__((ext_vector_type(4))) float;

static __device__ __forceinline__ short f2bf(float f) {
  union { float f; unsigned u; } v; v.f = f;
  unsigned r = v.u + 0x7fffu + ((v.u >> 16) & 1u);  // RNE
  return (short)(r >> 16);
}
static __device__ __forceinline__ float bf2f(short s) {
  union { unsigned u; float f; } v; v.u = ((unsigned)(unsigned short)s) << 16;
  return v.f;
}

// ---- degree counts, both relations in one launch ----
__global__ void count_edges2(const int* __restrict__ ev_s, const int* __restrict__ ev_d, int EV,
                             const int* __restrict__ el_s, const int* __restrict__ el_d, int EL,
                             int* __restrict__ cnt, int oV_u, int oV_p, int oL_u, int oL_p) {
  int i = blockIdx.x * blockDim.x + threadIdx.x;
  if (i < EV) {
    atomicAdd(&cnt[oV_u + ev_s[i]], 1);
    atomicAdd(&cnt[oV_p + ev_d[i]], 1);
  } else if (i - EV < EL) {
    int e = i - EV;
    atomicAdd(&cnt[oL_u + el_s[e]], 1);
    atomicAdd(&cnt[oL_p + el_d[e]], 1);
  }
}

// ---- 3-kernel exclusive scan over 4 contiguous count arrays ----
__global__ __launch_bounds__(256) void scan_k1(const int* __restrict__ cnt, int* __restrict__ off,
                                               int* __restrict__ bsums, int4 starts, int4 lens) {
  int a = blockIdx.y;
  int start = ((const int*)&starts)[a];
  int len   = ((const int*)&lens)[a];
  int chunk = blockIdx.x * 1024;
  if (chunk >= len) return;
  const int* in = cnt + start;
  int* out = off + start;
  int tid = threadIdx.x;
  int base = chunk + tid * 4;
  int v[4];
#pragma unroll
  for (int j = 0; j < 4; ++j) v[j] = (base + j < len) ? in[base + j] : 0;
  int s = v[0] + v[1] + v[2] + v[3];
  __shared__ int lds[256];
  lds[tid] = s; __syncthreads();
  for (int o = 1; o < 256; o <<= 1) {
    int t = (tid >= o) ? lds[tid - o] : 0;
    __syncthreads();
    lds[tid] += t;
    __syncthreads();
  }
  int run = lds[tid] - s;  // exclusive prefix of this thread's 4
#pragma unroll
  for (int j = 0; j < 4; ++j) { if (base + j < len) out[base + j] = run; run += v[j]; }
  if (tid == 255) bsums[a * 256 + blockIdx.x] = lds[255];
}

__global__ __launch_bounds__(256) void scan_k2(int* __restrict__ bsums, int4 lens) {
  int a = blockIdx.x;
  int len = ((const int*)&lens)[a];
  int nb = (len + 1023) >> 10;
  int tid = threadIdx.x;
  int s = (tid < nb) ? bsums[a * 256 + tid] : 0;  // guard: slots >= nb are poisoned
  __shared__ int lds[256];
  lds[tid] = s; __syncthreads();
  for (int o = 1; o < 256; o <<= 1) {
    int t = (tid >= o) ? lds[tid - o] : 0;
    __syncthreads();
    lds[tid] += t;
    __syncthreads();
  }
  bsums[a * 256 + tid] = lds[tid] - s;
}

__global__ __launch_bounds__(256) void scan_k3(int* __restrict__ off, const int* __restrict__ bsums,
                                               int4 starts, int4 lens) {
  int a = blockIdx.y;
  int start = ((const int*)&starts)[a];
  int len   = ((const int*)&lens)[a];
  int chunk = blockIdx.x * 1024;
  if (chunk >= len) return;
  int add = bsums[a * 256 + blockIdx.x];
  int* out = off + start;
  int base = chunk + threadIdx.x * 4;
#pragma unroll
  for (int j = 0; j < 4; ++j) if (base + j < len) out[base + j] += add;
}

// ---- CSR fill, both relations (both directions each) in one launch ----
__global__ void fill_csr2(const int* __restrict__ ev_s, const int* __restrict__ ev_d, int EV,
                          const int* __restrict__ el_s, const int* __restrict__ el_d, int EL,
                          const int* __restrict__ off, int* __restrict__ cur,
                          int* __restrict__ sV_p, int* __restrict__ sV_u,
                          int* __restrict__ sL_p, int* __restrict__ sL_u,
                          int oV_p, int oV_u, int oL_p, int oL_u) {
  int i = blockIdx.x * blockDim.x + threadIdx.x;
  if (i < EV) {
    int s = ev_s[i], d = ev_d[i];
    sV_p[off[oV_p + d] + atomicAdd(&cur[oV_p + d], 1)] = s;
    sV_u[off[oV_u + s] + atomicAdd(&cur[oV_u + s], 1)] = d;
  } else if (i - EV < EL) {
    int e = i - EV;
    int s = el_s[e], d = el_d[e];
    sL_p[off[oL_p + d] + atomicAdd(&cur[oL_p + d], 1)] = s;
    sL_u[off[oL_u + s] + atomicAdd(&cur[oL_u + s], 1)] = d;
  }
}

// ---- fp32 -> bf16 streaming convert, both embeddings in one launch ----
__global__ void cvt_bf16_2(const float* __restrict__ inU, short* __restrict__ outU, int nU,
                           const float* __restrict__ inP, short* __restrict__ outP, int nP) {
  int idx = (blockIdx.x * blockDim.x + threadIdx.x) * 4;
  const float* in; short* out;
  if (idx < nU) { in = inU + idx; out = outU + idx; }
  else {
    idx -= nU;
    if (idx >= nP) return;
    in = inP + idx; out = outP + idx;
  }
  float4 v = *(const float4*)in;
  short4 o = { f2bf(v.x), f2bf(v.y), f2bf(v.z), f2bf(v.w) };
  *(short4*)out = o;
}

// ---- weight prep: bf16 convert, combine Wr pair and bias pair per (layer,type).
// Weights written in MFMA B-fragment order:
//   fragment (jt,kk), lane l holds 8 bf16 of W[(jt*16 + (l&15))][kk*32 + (l>>4)*8 + j]
//   stored at ((jt*4+kk)*64 + l)*8 + j
static __device__ __forceinline__ int wswz(int e) {
  int n = e >> 7, k = e & 127;          // W row-major [n][k]
  int jt = n >> 4, r = n & 15;
  int kk = k >> 5, q = (k >> 3) & 3, j = k & 7;
  return (((jt * 4 + kk) * 64 + q * 16 + r) << 3) + j;
}
__global__ void prep_weights(const float* __restrict__ W_l, const float* __restrict__ b_l,
                             const float* __restrict__ W_r,
                             short* __restrict__ Wbf, float* __restrict__ bc) {
  int i = blockIdx.x * blockDim.x + threadIdx.x;
  if (i >= 4 * 16384) return;
  int s = i >> 14, e = i & 16383;
  int l = s >> 1, t = s & 1;
  int rA = t ? 1 : 0, rB = t ? 3 : 2;
  const float* WA = W_l + ((size_t)(l * 4 + rA) << 14);
  const float* WB = W_l + ((size_t)(l * 4 + rB) << 14);
  const float* RA = W_r + ((size_t)(l * 4 + rA) << 14);
  const float* RB = W_r + ((size_t)(l * 4 + rB) << 14);
  short* o = Wbf + (size_t)s * 3 * 16384;
  int d = wswz(e);
  o[d]             = f2bf(WA[e]);
  o[16384 + d]     = f2bf(WB[e]);
  o[2 * 16384 + d] = f2bf(RA[e] + RB[e]);
  if (e < H) bc[s * H + e] = b_l[(l * 4 + rA) * H + e] + b_l[(l * 4 + rB) * H + e];
}

// ---- fused segment-mean for BOTH parts (posts + users) in one launch.
// 16 lanes per node, bf16x8 per lane, fp32 accum. x4-unrolled gathers (4 in
// flight). L-relation's first two gathers issued BEFORE V's finalize drain
// (in-order vmcnt completes them for free while waiting on V's last gather).
// PLAIN stores for mV/mL: they are re-read by fused_gemm2 one launch later,
// L3 residency is worth more than write-stream hygiene (r5 lesson: nt-stores
// here cost +100 MB of HBM re-fetch in the consumer).
__global__ __launch_bounds__(256) void aggregate2(
    const bf16x8* __restrict__ xA,
    const int* __restrict__ sVA, const int* __restrict__ oVA, const int* __restrict__ cVA,
    const int* __restrict__ sLA, const int* __restrict__ oLA, const int* __restrict__ cLA,
    bf16x8* __restrict__ mVA, bf16x8* __restrict__ mLA, int NA, int nbA,
    const bf16x8* __restrict__ xB,
    const int* __restrict__ sVB, const int* __restrict__ oVB, const int* __restrict__ cVB,
    const int* __restrict__ sLB, const int* __restrict__ oLB, const int* __restrict__ cLB,
    bf16x8* __restrict__ mVB, bf16x8* __restrict__ mLB, int NB) {
  int b = blockIdx.x;
  const bf16x8* x; const int *sV, *oV, *cV, *sL, *oL, *cL;
  bf16x8 *mV, *mL; int N, t0;
  if (b < nbA) {
    x = xA; sV = sVA; oV = oVA; cV = cVA; sL = sLA; oL = oLA; cL = cLA;
    mV = mVA; mL = mLA; N = NA; t0 = b * 256;
  } else {
    x = xB; sV = sVB; oV = oVB; cV = cVB; sL = sLB; oL = oLB; cL = cLB;
    mV = mVB; mL = mLB; N = NB; t0 = (b - nbA) * 256;
  }
  int t = t0 + threadIdx.x;
  int node = t >> 4, c = t & 15;
  if (node >= N) return;

  int oVn = oV[node], nV = cV[node];
  int oLn = oL[node], nL = cL[node];

  // prefetch L's first two gathers so they overlap V's chain
  bf16x8 pAL{}, pBL{};
  if (nL > 0) pAL = x[(size_t)sL[oLn] * 16 + c];
  if (nL > 1) pBL = x[(size_t)sL[oLn + 1] * 16 + c];

  float acc[8];
  {  // V relation
#pragma unroll
    for (int j = 0; j < 8; ++j) acc[j] = 0.f;
    int i = 0;
    for (; i + 4 <= nV; i += 4) {
      int s0 = sV[oVn + i], s1 = sV[oVn + i + 1], s2 = sV[oVn + i + 2], s3 = sV[oVn + i + 3];
      bf16x8 v0 = x[(size_t)s0 * 16 + c];
      bf16x8 v1 = x[(size_t)s1 * 16 + c];
      bf16x8 v2 = x[(size_t)s2 * 16 + c];
      bf16x8 v3 = x[(size_t)s3 * 16 + c];
#pragma unroll
      for (int j = 0; j < 8; ++j) acc[j] += bf2f(v0[j]);
#pragma unroll
      for (int j = 0; j < 8; ++j) acc[j] += bf2f(v1[j]);
#pragma unroll
      for (int j = 0; j < 8; ++j) acc[j] += bf2f(v2[j]);
#pragma unroll
      for (int j = 0; j < 8; ++j) acc[j] += bf2f(v3[j]);
    }
    for (; i < nV; ++i) {
      bf16x8 v = x[(size_t)sV[oVn + i] * 16 + c];
#pragma unroll
      for (int j = 0; j < 8; ++j) acc[j] += bf2f(v[j]);
    }
    float rin = 1.0f / fmaxf((float)nV, 1.0f);
    bf16x8 w;
#pragma unroll
    for (int j = 0; j < 8; ++j) w[j] = f2bf(acc[j] * rin);
    mV[(size_t)node * 16 + c] = w;
  }
  {  // L relation (first two already in pAL/pBL)
#pragma unroll
    for (int j = 0; j < 8; ++j) acc[j] = 0.f;
    if (nL > 0) {
#pragma unroll
      for (int j = 0; j < 8; ++j) acc[j] += bf2f(pAL[j]);
    }
    if (nL > 1) {
#pragma unroll
      for (int j = 0; j < 8; ++j) acc[j] += bf2f(pBL[j]);
    }
    int i = 2;
    for (; i + 4 <= nL; i += 4) {
      int s0 = sL[oLn + i], s1 = sL[oLn + i + 1], s2 = sL[oLn + i + 2], s3 = sL[oLn + i + 3];
      bf16x8 v0 = x[(size_t)s0 * 16 + c];
      bf16x8 v1 = x[(size_t)s1 * 16 + c];
      bf16x8 v2 = x[(size_t)s2 * 16 + c];
      bf16x8 v3 = x[(size_t)s3 * 16 + c];
#pragma unroll
      for (int j = 0; j < 8; ++j) acc[j] += bf2f(v0[j]);
#pragma unroll
      for (int j = 0; j < 8; ++j) acc[j] += bf2f(v1[j]);
#pragma unroll
      for (int j = 0; j < 8; ++j) acc[j] += bf2f(v2[j]);
#pragma unroll
      for (int j = 0; j < 8; ++j) acc[j] += bf2f(v3[j]);
    }
    for (; i < nL; ++i) {
      bf16x8 v = x[(size_t)sL[oLn + i] * 16 + c];
#pragma unroll
      for (int j = 0; j < 8; ++j) acc[j] += bf2f(v[j]);
    }
    float rin = 1.0f / fmaxf((float)nL, 1.0f);
    bf16x8 w;
#pragma unroll
    for (int j = 0; j < 8; ++j) w[j] = f2bf(acc[j] * rin);
    mL[(size_t)node * 16 + c] = w;
  }
}

// ---- fused SAGE transform (r2 structure): out = mV@WA.T + mL@WB.T + x@WRc.T + b [, ReLU]
// Both parts in ONE launch: 256 blocks x 512 threads, 96 KB dynamic LDS.
// All 3 weight matrices staged ONCE per block (fragment-order, linear copy),
// exactly one __syncthreads, then 8 waves free-run over 32-row groups with a
// 3-deep rotating A-fragment pipeline. launch_bounds(512,1): LDS caps us at
// 1 block/CU anyway, so let the register allocator breathe (r4/r5 lesson:
// forcing min-waves spills -> WRITE_SIZE inflation).
// A frag: A[m=lane&15][k=quad*8+j]; B frag: B[k][n=lane&15]=W[n][k];
// C/D: col=lane&15, row=quad*4+reg.
__global__ __launch_bounds__(512, 1) void fused_gemm2(
    const short* __restrict__ mVA, const short* __restrict__ mLA, const short* __restrict__ xbA,
    const short* __restrict__ WAp, const float* __restrict__ biasA,
    float* __restrict__ o32A, short* __restrict__ o16A, int NA, int nbA,
    const short* __restrict__ mVB, const short* __restrict__ mLB, const short* __restrict__ xbB,
    const short* __restrict__ WBp, const float* __restrict__ biasB,
    float* __restrict__ o32B, short* __restrict__ o16B, int NB, int relu) {
  extern __shared__ short Wlds[];  // 3 * 16384 shorts = 96 KB
  int b = blockIdx.x;
  const short *mV, *mL, *xb, *W; const float* bias;
  float* out32; short* out16; int N, nbPart, bLoc;
  if (b < nbA) {
    mV = mVA; mL = mLA; xb = xbA; W = WAp; bias = biasA;
    out32 = o32A; out16 = o16A; N = NA; nbPart = nbA; bLoc = b;
  } else {
    mV = mVB; mL = mLB; xb = xbB; W = WBp; bias = biasB;
    out32 = o32B; out16 = o16B; N = NB; nbPart = gridDim.x - nbA; bLoc = b - nbA;
  }

  int tid = threadIdx.x;
  // stage all 3 matrices (6144 x 16B chunks), coalesced linear copy
#pragma unroll
  for (int it = 0; it < 12; ++it) {
    int c = it * 512 + tid;
    *(bf16x8*)(Wlds + (size_t)c * 8) = *(const bf16x8*)(W + (size_t)c * 8);
  }
  __syncthreads();  // the ONLY barrier

  int wave = tid >> 6, lane = tid & 63;
  int r = lane & 15, quad = lane >> 4;

  float bias_r[8];
#pragma unroll
  for (int jt = 0; jt < 8; ++jt) bias_r[jt] = bias[jt * 16 + r];

  int nrgTot = (N + 31) >> 5;
  int wStride = nbPart * 8;
  int wBase = bLoc * 8 + wave;
  int nrgW = (wBase < nrgTot) ? (nrgTot - wBase + wStride - 1) / wStride : 0;

  floatx4 acc[2][8];
#pragma unroll
  for (int t = 0; t < 2; ++t)
#pragma unroll
    for (int j = 0; j < 8; ++j) acc[t][j] = floatx4{0.f, 0.f, 0.f, 0.f};

  auto issueA = [&](int j, int m, bf16x8 (&buf)[2][4]) {
    if (j >= nrgW) return;  // wave-uniform
    int rowb = (wBase + j * wStride) << 5;
    const short* X = (m == 0) ? mV : (m == 1) ? mL : xb;
#pragma unroll
    for (int t = 0; t < 2; ++t) {
      int row = rowb + t * 16 + r;
      row = row < N ? row : N - 1;
      const short* Xr = X + (size_t)row * H + quad * 8;
#pragma unroll
      for (int kk = 0; kk < 4; ++kk) buf[t][kk] = *(const bf16x8*)(Xr + kk * 32);
    }
  };

  auto computeB = [&](int m, bf16x8 (&buf)[2][4]) {
    const short* Wm = Wlds + m * 16384;
#pragma unroll
    for (int kk = 0; kk < 4; ++kk) {
#pragma unroll
      for (int jt = 0; jt < 8; ++jt) {
        bf16x8 bfR = *(const bf16x8*)(Wm + (size_t)((jt * 4 + kk) * 64 + lane) * 8);
        acc[0][jt] = __builtin_amdgcn_mfma_f32_16x16x32_bf16(buf[0][kk], bfR, acc[0][jt], 0, 0, 0);
        acc[1][jt] = __builtin_amdgcn_mfma_f32_16x16x32_bf16(buf[1][kk], bfR, acc[1][jt], 0, 0, 0);
      }
    }
  };

  auto epi = [&](int j) {
    int rowb = (wBase + j * wStride) << 5;
#pragma unroll
    for (int t = 0; t < 2; ++t) {
#pragma unroll
      for (int jt = 0; jt < 8; ++jt) {
        int ocol = jt * 16 + r;
        float bv = bias_r[jt];
#pragma unroll
        for (int g = 0; g < 4; ++g) {
          int orow = rowb + t * 16 + quad * 4 + g;
          if (orow < N) {
            float v = acc[t][jt][g] + bv;
            if (relu) v = fmaxf(v, 0.f);
            if (out32) out32[(size_t)orow * H + ocol] = v;
            else       out16[(size_t)orow * H + ocol] = f2bf(v);
          }
        }
        acc[t][jt] = floatx4{0.f, 0.f, 0.f, 0.f};
      }
    }
  };

  bf16x8 A0[2][4], A1[2][4], A2[2][4];
  issueA(0, 0, A0);
  issueA(0, 1, A1);
  for (int j = 0; j < nrgW; ++j) {
    issueA(j, 2, A2);
    computeB(0, A0);
    issueA(j + 1, 0, A0);
    computeB(1, A1);
    issueA(j + 1, 1, A1);
    computeB(2, A2);
    epi(j);
  }
}

extern "C" void kernel_launch(void* const* d_in, const int* in_sizes, int n_in,
                              void* d_out, int out_size, void* d_ws, size_t ws_size,
                              hipStream_t stream) {
  const float* emb_user = (const float*)d_in[0];
  const float* emb_post = (const float*)d_in[1];
  const float* W_l = (const float*)d_in[2];
  const float* b_l = (const float*)d_in[3];
  const float* W_r = (const float*)d_in[4];
  const int* ev_s = (const int*)d_in[5];
  const int* ev_d = (const int*)d_in[6];
  const int* el_s = (const int*)d_in[7];
  const int* el_d = (const int*)d_in[8];

  const int NU = in_sizes[0] / H;
  const int NP = in_sizes[1] / H;
  const int EV = in_sizes[5];
  const int EL = in_sizes[7];
  const int T = 2 * NP + 2 * NU;
  const size_t NUH = (size_t)NU * H, NPH = (size_t)NP * H;

  // workspace carve (256B-aligned bumps)
  char* p = (char*)d_ws;
  auto alloc = [&](size_t bytes) -> void* {
    void* q = (void*)p; p += (bytes + 255) & ~(size_t)255; return q;
  };
  int*   cnt   = (int*)alloc((size_t)T * 4);
  int*   cur   = (int*)alloc((size_t)T * 4);
  int*   off   = (int*)alloc((size_t)T * 4);
  int*   bsums = (int*)alloc(4 * 256 * 4);
  int*   sV_p  = (int*)alloc((size_t)EV * 4);
  int*   sV_u  = (int*)alloc((size_t)EV * 4);
  int*   sL_p  = (int*)alloc((size_t)EL * 4);
  int*   sL_u  = (int*)alloc((size_t)EL * 4);
  short* Wbf   = (short*)alloc((size_t)4 * 3 * 16384 * 2);
  float* bc    = (float*)alloc(4 * H * 4);
  short* xbf_u  = (short*)alloc(NUH * 2);
  short* xbf_p  = (short*)alloc(NPH * 2);
  short* xbf1_u = (short*)alloc(NUH * 2);
  short* xbf1_p = (short*)alloc(NPH * 2);
  short* mVp    = (short*)alloc(NPH * 2);
  short* mLp    = (short*)alloc(NPH * 2);
  short* mVu    = (short*)alloc(NUH * 2);
  short* mLu    = (short*)alloc(NUH * 2);

  float* out_u_final = (float*)d_out;
  float* out_p_final = (float*)d_out + NUH;

  // count-array index order: {V_p:0, L_p:NP, V_u:2NP, L_u:2NP+NU}
  const int oV_p = 0, oL_p = NP, oV_u = 2 * NP, oL_u = 2 * NP + NU;

  hipMemsetAsync(cnt, 0, (size_t)T * 4, stream);
  hipMemsetAsync(cur, 0, (size_t)T * 4, stream);
  count_edges2<<<(EV + EL + 255) / 256, 256, 0, stream>>>(
      ev_s, ev_d, EV, el_s, el_d, EL, cnt, oV_u, oV_p, oL_u, oL_p);

  int4 starts = { oV_p, oL_p, oV_u, oL_u };
  int4 lens   = { NP, NP, NU, NU };
  int maxb = ((NP > NU ? NP : NU) + 1023) / 1024;
  dim3 gscan(maxb, 4, 1);
  scan_k1<<<gscan, 256, 0, stream>>>(cnt, off, bsums, starts, lens);
  scan_k2<<<4, 256, 0, stream>>>(bsums, lens);
  scan_k3<<<gscan, 256, 0, stream>>>(off, bsums, starts, lens);

  fill_csr2<<<(EV + EL + 255) / 256, 256, 0, stream>>>(
      ev_s, ev_d, EV, el_s, el_d, EL, off, cur,
      sV_p, sV_u, sL_p, sL_u, oV_p, oV_u, oL_p, oL_u);

  cvt_bf16_2<<<((int)((NUH + NPH) / 4) + 255) / 256, 256, 0, stream>>>(
      emb_user, xbf_u, (int)NUH, emb_post, xbf_p, (int)NPH);
  prep_weights<<<(4 * 16384 + 255) / 256, 256, 0, stream>>>(W_l, b_l, W_r, Wbf, bc);

  // 96 KB dynamic LDS for the fused GEMM
  const int ldsBytes = 3 * 16384 * 2;
  hipFuncSetAttribute((const void*)fused_gemm2, hipFuncAttributeMaxDynamicSharedMemorySize,
                      ldsBytes);

  // aggregate grid split (16 nodes per 256-thread block)
  int nbAggP = (NP + 15) / 16;
  int nbAggU = (NU + 15) / 16;

  // gemm grid: 256 blocks (1/CU, LDS-capped), split proportional to rows
  const int GB = 256;
  int nbP = (int)(((long long)GB * NP) / ((long long)NP + NU));
  if (nbP < 1) nbP = 1;
  if (nbP > GB - 1) nbP = GB - 1;

  for (int l = 0; l < 2; ++l) {
    const short* xu = l ? xbf1_u : xbf_u;
    const short* xp = l ? xbf1_p : xbf_p;
    const short* Wpost = Wbf + (size_t)(l * 2 + 0) * 3 * 16384;
    const short* Wuser = Wbf + (size_t)(l * 2 + 1) * 3 * 16384;
    const float* bpost = bc + (l * 2 + 0) * H;
    const float* buser = bc + (l * 2 + 1) * H;

    // both aggregations (posts from users, users from posts) in one launch
    aggregate2<<<nbAggP + nbAggU, 256, 0, stream>>>(
        (const bf16x8*)xu,
        sV_p, off + oV_p, cnt + oV_p,
        sL_p, off + oL_p, cnt + oL_p,
        (bf16x8*)mVp, (bf16x8*)mLp, NP, nbAggP,
        (const bf16x8*)xp,
        sV_u, off + oV_u, cnt + oV_u,
        sL_u, off + oL_u, cnt + oL_u,
        (bf16x8*)mVu, (bf16x8*)mLu, NU);

    // both transforms in one launch
    fused_gemm2<<<GB, 512, ldsBytes, stream>>>(
        mVp, mLp, xp, Wpost, bpost,
        l ? out_p_final : nullptr, l ? nullptr : xbf1_p, NP, nbP,
        mVu, mLu, xu, Wuser, buser,
        l ? out_u_final : nullptr, l ? nullptr : xbf1_u, NU, l == 0);
  }
}

// Round 7
// 665.333 us; speedup vs baseline: 2.4183x; 1.0981x over previous
//
#include <hip/hip_runtime.h>
#include <hip/hip_bf16.h>

#define H 128

using bf16x8  = __attribute__((ext_vector_type(8))) short;  // 8 bf16 = 4 VGPRs
using floatx4 = __attribute__((ext_vector_type(4))) float;

static __device__ __forceinline__ short f2bf(float f) {
  union { float f; unsigned u; } v; v.f = f;
  unsigned r = v.u + 0x7fffu + ((v.u >> 16) & 1u);  // RNE
  return (short)(r >> 16);
}
static __device__ __forceinline__ float bf2f(short s) {
  union { unsigned u; float f; } v; v.u = ((unsigned)(unsigned short)s) << 16;
  return v.f;
}

// ---- fused preprocessing A: degree counts + per-edge slot record (atomic
// return value), fp32->bf16 embedding convert, weight prep -- all mutually
// independent, one launch. Count blocks first (long atomic latency chains
// start early); streaming cvt/prep blocks fill the machine behind them.
// Recording slot here makes fill_csr3 atomic-free (r6 lesson: fill's 100 us
// was random RMW + line thrash; the RMW half rides the count pass for free).
__global__ __launch_bounds__(256) void preproc_a(
    const int* __restrict__ ev_s, const int* __restrict__ ev_d, int EV,
    const int* __restrict__ el_s, const int* __restrict__ el_d, int EL,
    int* __restrict__ cnt, int oV_u, int oV_p, int oL_u, int oL_p,
    int* __restrict__ slotVp, int* __restrict__ slotVu,
    int* __restrict__ slotLp, int* __restrict__ slotLu,
    const float* __restrict__ embU, short* __restrict__ xbfU, int nU,
    const float* __restrict__ embP, short* __restrict__ xbfP, int nP,
    const float* __restrict__ W_l, const float* __restrict__ b_l,
    const float* __restrict__ W_r,
    short* __restrict__ Wbf, float* __restrict__ bc, int nbCnt, int nbCvt);

// ---- 3-kernel exclusive scan over 4 contiguous count arrays ----
__global__ __launch_bounds__(256) void scan_k1(const int* __restrict__ cnt, int* __restrict__ off,
                                               int* __restrict__ bsums, int4 starts, int4 lens) {
  int a = blockIdx.y;
  int start = ((const int*)&starts)[a];
  int len   = ((const int*)&lens)[a];
  int chunk = blockIdx.x * 1024;
  if (chunk >= len) return;
  const int* in = cnt + start;
  int* out = off + start;
  int tid = threadIdx.x;
  int base = chunk + tid * 4;
  int v[4];
#pragma unroll
  for (int j = 0; j < 4; ++j) v[j] = (base + j < len) ? in[base + j] : 0;
  int s = v[0] + v[1] + v[2] + v[3];
  __shared__ int lds[256];
  lds[tid] = s; __syncthreads();
  for (int o = 1; o < 256; o <<= 1) {
    int t = (tid >= o) ? lds[tid - o] : 0;
    __syncthreads();
    lds[tid] += t;
    __syncthreads();
  }
  int run = lds[tid] - s;  // exclusive prefix of this thread's 4
#pragma unroll
  for (int j = 0; j < 4; ++j) { if (base + j < len) out[base + j] = run; run += v[j]; }
  if (tid == 255) bsums[a * 256 + blockIdx.x] = lds[255];
}

__global__ __launch_bounds__(256) void scan_k2(int* __restrict__ bsums, int4 lens) {
  int a = blockIdx.x;
  int len = ((const int*)&lens)[a];
  int nb = (len + 1023) >> 10;
  int tid = threadIdx.x;
  int s = (tid < nb) ? bsums[a * 256 + tid] : 0;  // guard: slots >= nb are poisoned
  __shared__ int lds[256];
  lds[tid] = s; __syncthreads();
  for (int o = 1; o < 256; o <<= 1) {
    int t = (tid >= o) ? lds[tid - o] : 0;
    __syncthreads();
    lds[tid] += t;
    __syncthreads();
  }
  bsums[a * 256 + tid] = lds[tid] - s;
}

__global__ __launch_bounds__(256) void scan_k3(int* __restrict__ off, const int* __restrict__ bsums,
                                               int4 starts, int4 lens) {
  int a = blockIdx.y;
  int start = ((const int*)&starts)[a];
  int len   = ((const int*)&lens)[a];
  int chunk = blockIdx.x * 1024;
  if (chunk >= len) return;
  int add = bsums[a * 256 + blockIdx.x];
  int* out = off + start;
  int base = chunk + threadIdx.x * 4;
#pragma unroll
  for (int j = 0; j < 4; ++j) if (base + j < len) out[base + j] += add;
}

__global__ __launch_bounds__(256) void preproc_a(
    const int* __restrict__ ev_s, const int* __restrict__ ev_d, int EV,
    const int* __restrict__ el_s, const int* __restrict__ el_d, int EL,
    int* __restrict__ cnt, int oV_u, int oV_p, int oL_u, int oL_p,
    int* __restrict__ slotVp, int* __restrict__ slotVu,
    int* __restrict__ slotLp, int* __restrict__ slotLu,
    const float* __restrict__ embU, short* __restrict__ xbfU, int nU,
    const float* __restrict__ embP, short* __restrict__ xbfP, int nP,
    const float* __restrict__ W_l, const float* __restrict__ b_l,
    const float* __restrict__ W_r,
    short* __restrict__ Wbf, float* __restrict__ bc, int nbCnt, int nbCvt) {
  int b = blockIdx.x;
  if (b < nbCnt) {
    // ---- count + slot record ----
    int i = b * 256 + threadIdx.x;
    if (i < EV) {
      int s = ev_s[i], d = ev_d[i];
      slotVu[i] = atomicAdd(&cnt[oV_u + s], 1);
      slotVp[i] = atomicAdd(&cnt[oV_p + d], 1);
    } else if (i - EV < EL) {
      int e = i - EV;
      int s = el_s[e], d = el_d[e];
      slotLu[e] = atomicAdd(&cnt[oL_u + s], 1);
      slotLp[e] = atomicAdd(&cnt[oL_p + d], 1);
    }
  } else if (b < nbCnt + nbCvt) {
    // ---- fp32 -> bf16 convert (both embeddings) ----
    int idx = ((b - nbCnt) * 256 + threadIdx.x) * 4;
    const float* in; short* out;
    if (idx < nU) { in = embU + idx; out = xbfU + idx; }
    else {
      idx -= nU;
      if (idx >= nP) return;
      in = embP + idx; out = xbfP + idx;
    }
    float4 v = *(const float4*)in;
    short4 o = { f2bf(v.x), f2bf(v.y), f2bf(v.z), f2bf(v.w) };
    *(short4*)out = o;
  } else {
    // ---- weight prep: bf16 convert, combine Wr pair and bias pair, write in
    // MFMA B-fragment order: frag (jt,kk), lane l holds 8 bf16 of
    // W[(jt*16+(l&15))][kk*32+(l>>4)*8+j] stored at ((jt*4+kk)*64+l)*8+j ----
    int i = (b - nbCnt - nbCvt) * 256 + threadIdx.x;
    if (i >= 4 * 16384) return;
    int s = i >> 14, e = i & 16383;
    int l = s >> 1, t = s & 1;
    int rA = t ? 1 : 0, rB = t ? 3 : 2;
    const float* WA = W_l + ((size_t)(l * 4 + rA) << 14);
    const float* WB = W_l + ((size_t)(l * 4 + rB) << 14);
    const float* RA = W_r + ((size_t)(l * 4 + rA) << 14);
    const float* RB = W_r + ((size_t)(l * 4 + rB) << 14);
    short* o = Wbf + (size_t)s * 3 * 16384;
    int n = e >> 7, k = e & 127;
    int jt = n >> 4, r = n & 15;
    int kk = k >> 5, q = (k >> 3) & 3, j = k & 7;
    int d = (((jt * 4 + kk) * 64 + q * 16 + r) << 3) + j;
    o[d]             = f2bf(WA[e]);
    o[16384 + d]     = f2bf(WB[e]);
    o[2 * 16384 + d] = f2bf(RA[e] + RB[e]);
    if (e < H) bc[s * H + e] = b_l[(l * 4 + rA) * H + e] + b_l[(l * 4 + rB) * H + e];
  }
}

// ---- CSR fill, ATOMIC-FREE: position = off[node] + slot[edge] (slot was
// recorded by the count pass). Streamed reads + one random 4B store per entry.
__global__ void fill_csr3(const int* __restrict__ ev_s, const int* __restrict__ ev_d, int EV,
                          const int* __restrict__ el_s, const int* __restrict__ el_d, int EL,
                          const int* __restrict__ off,
                          const int* __restrict__ slotVp, const int* __restrict__ slotVu,
                          const int* __restrict__ slotLp, const int* __restrict__ slotLu,
                          int* __restrict__ sV_p, int* __restrict__ sV_u,
                          int* __restrict__ sL_p, int* __restrict__ sL_u,
                          int oV_p, int oV_u, int oL_p, int oL_u) {
  int i = blockIdx.x * blockDim.x + threadIdx.x;
  if (i < EV) {
    int s = ev_s[i], d = ev_d[i];
    sV_p[off[oV_p + d] + slotVp[i]] = s;
    sV_u[off[oV_u + s] + slotVu[i]] = d;
  } else if (i - EV < EL) {
    int e = i - EV;
    int s = el_s[e], d = el_d[e];
    sL_p[off[oL_p + d] + slotLp[e]] = s;
    sL_u[off[oL_u + s] + slotLu[e]] = d;
  }
}

// ---- fused segment-mean for BOTH parts (posts + users) in one launch.
// 16 lanes per node, bf16x8 per lane, fp32 accum. x4-unrolled gathers (4 in
// flight). L-relation's first two gathers issued BEFORE V's finalize drain
// (in-order vmcnt completes them for free while waiting on V's last gather).
// PLAIN stores for mV/mL: they are re-read by fused_gemm2 one launch later,
// L3 residency is worth more than write-stream hygiene (r5 lesson: nt-stores
// here cost +100 MB of HBM re-fetch in the consumer).
__global__ __launch_bounds__(256) void aggregate2(
    const bf16x8* __restrict__ xA,
    const int* __restrict__ sVA, const int* __restrict__ oVA, const int* __restrict__ cVA,
    const int* __restrict__ sLA, const int* __restrict__ oLA, const int* __restrict__ cLA,
    bf16x8* __restrict__ mVA, bf16x8* __restrict__ mLA, int NA, int nbA,
    const bf16x8* __restrict__ xB,
    const int* __restrict__ sVB, const int* __restrict__ oVB, const int* __restrict__ cVB,
    const int* __restrict__ sLB, const int* __restrict__ oLB, const int* __restrict__ cLB,
    bf16x8* __restrict__ mVB, bf16x8* __restrict__ mLB, int NB) {
  int b = blockIdx.x;
  const bf16x8* x; const int *sV, *oV, *cV, *sL, *oL, *cL;
  bf16x8 *mV, *mL; int N, t0;
  if (b < nbA) {
    x = xA; sV = sVA; oV = oVA; cV = cVA; sL = sLA; oL = oLA; cL = cLA;
    mV = mVA; mL = mLA; N = NA; t0 = b * 256;
  } else {
    x = xB; sV = sVB; oV = oVB; cV = cVB; sL = sLB; oL = oLB; cL = cLB;
    mV = mVB; mL = mLB; N = NB; t0 = (b - nbA) * 256;
  }
  int t = t0 + threadIdx.x;
  int node = t >> 4, c = t & 15;
  if (node >= N) return;

  int oVn = oV[node], nV = cV[node];
  int oLn = oL[node], nL = cL[node];

  // prefetch L's first two gathers so they overlap V's chain
  bf16x8 pAL{}, pBL{};
  if (nL > 0) pAL = x[(size_t)sL[oLn] * 16 + c];
  if (nL > 1) pBL = x[(size_t)sL[oLn + 1] * 16 + c];

  float acc[8];
  {  // V relation
#pragma unroll
    for (int j = 0; j < 8; ++j) acc[j] = 0.f;
    int i = 0;
    for (; i + 4 <= nV; i += 4) {
      int s0 = sV[oVn + i], s1 = sV[oVn + i + 1], s2 = sV[oVn + i + 2], s3 = sV[oVn + i + 3];
      bf16x8 v0 = x[(size_t)s0 * 16 + c];
      bf16x8 v1 = x[(size_t)s1 * 16 + c];
      bf16x8 v2 = x[(size_t)s2 * 16 + c];
      bf16x8 v3 = x[(size_t)s3 * 16 + c];
#pragma unroll
      for (int j = 0; j < 8; ++j) acc[j] += bf2f(v0[j]);
#pragma unroll
      for (int j = 0; j < 8; ++j) acc[j] += bf2f(v1[j]);
#pragma unroll
      for (int j = 0; j < 8; ++j) acc[j] += bf2f(v2[j]);
#pragma unroll
      for (int j = 0; j < 8; ++j) acc[j] += bf2f(v3[j]);
    }
    for (; i < nV; ++i) {
      bf16x8 v = x[(size_t)sV[oVn + i] * 16 + c];
#pragma unroll
      for (int j = 0; j < 8; ++j) acc[j] += bf2f(v[j]);
    }
    float rin = 1.0f / fmaxf((float)nV, 1.0f);
    bf16x8 w;
#pragma unroll
    for (int j = 0; j < 8; ++j) w[j] = f2bf(acc[j] * rin);
    mV[(size_t)node * 16 + c] = w;
  }
  {  // L relation (first two already in pAL/pBL)
#pragma unroll
    for (int j = 0; j < 8; ++j) acc[j] = 0.f;
    if (nL > 0) {
#pragma unroll
      for (int j = 0; j < 8; ++j) acc[j] += bf2f(pAL[j]);
    }
    if (nL > 1) {
#pragma unroll
      for (int j = 0; j < 8; ++j) acc[j] += bf2f(pBL[j]);
    }
    int i = 2;
    for (; i + 4 <= nL; i += 4) {
      int s0 = sL[oLn + i], s1 = sL[oLn + i + 1], s2 = sL[oLn + i + 2], s3 = sL[oLn + i + 3];
      bf16x8 v0 = x[(size_t)s0 * 16 + c];
      bf16x8 v1 = x[(size_t)s1 * 16 + c];
      bf16x8 v2 = x[(size_t)s2 * 16 + c];
      bf16x8 v3 = x[(size_t)s3 * 16 + c];
#pragma unroll
      for (int j = 0; j < 8; ++j) acc[j] += bf2f(v0[j]);
#pragma unroll
      for (int j = 0; j < 8; ++j) acc[j] += bf2f(v1[j]);
#pragma unroll
      for (int j = 0; j < 8; ++j) acc[j] += bf2f(v2[j]);
#pragma unroll
      for (int j = 0; j < 8; ++j) acc[j] += bf2f(v3[j]);
    }
    for (; i < nL; ++i) {
      bf16x8 v = x[(size_t)sL[oLn + i] * 16 + c];
#pragma unroll
      for (int j = 0; j < 8; ++j) acc[j] += bf2f(v[j]);
    }
    float rin = 1.0f / fmaxf((float)nL, 1.0f);
    bf16x8 w;
#pragma unroll
    for (int j = 0; j < 8; ++j) w[j] = f2bf(acc[j] * rin);
    mL[(size_t)node * 16 + c] = w;
  }
}

// ---- fused SAGE transform (r2 structure): out = mV@WA.T + mL@WB.T + x@WRc.T + b [, ReLU]
// Both parts in ONE launch: 256 blocks x 512 threads, 96 KB dynamic LDS.
// All 3 weight matrices staged ONCE per block (fragment-order, linear copy),
// exactly one __syncthreads, then 8 waves free-run over 32-row groups with a
// 3-deep rotating A-fragment pipeline. launch_bounds(512,1): LDS caps us at
// 1 block/CU anyway, so let the register allocator breathe (r4/r5 lesson:
// forcing min-waves spills -> WRITE_SIZE inflation).
// A frag: A[m=lane&15][k=quad*8+j]; B frag: B[k][n=lane&15]=W[n][k];
// C/D: col=lane&15, row=quad*4+reg.
__global__ __launch_bounds__(512, 1) void fused_gemm2(
    const short* __restrict__ mVA, const short* __restrict__ mLA, const short* __restrict__ xbA,
    const short* __restrict__ WAp, const float* __restrict__ biasA,
    float* __restrict__ o32A, short* __restrict__ o16A, int NA, int nbA,
    const short* __restrict__ mVB, const short* __restrict__ mLB, const short* __restrict__ xbB,
    const short* __restrict__ WBp, const float* __restrict__ biasB,
    float* __restrict__ o32B, short* __restrict__ o16B, int NB, int relu) {
  extern __shared__ short Wlds[];  // 3 * 16384 shorts = 96 KB
  int b = blockIdx.x;
  const short *mV, *mL, *xb, *W; const float* bias;
  float* out32; short* out16; int N, nbPart, bLoc;
  if (b < nbA) {
    mV = mVA; mL = mLA; xb = xbA; W = WAp; bias = biasA;
    out32 = o32A; out16 = o16A; N = NA; nbPart = nbA; bLoc = b;
  } else {
    mV = mVB; mL = mLB; xb = xbB; W = WBp; bias = biasB;
    out32 = o32B; out16 = o16B; N = NB; nbPart = gridDim.x - nbA; bLoc = b - nbA;
  }

  int tid = threadIdx.x;
  // stage all 3 matrices (6144 x 16B chunks), coalesced linear copy
#pragma unroll
  for (int it = 0; it < 12; ++it) {
    int c = it * 512 + tid;
    *(bf16x8*)(Wlds + (size_t)c * 8) = *(const bf16x8*)(W + (size_t)c * 8);
  }
  __syncthreads();  // the ONLY barrier

  int wave = tid >> 6, lane = tid & 63;
  int r = lane & 15, quad = lane >> 4;

  float bias_r[8];
#pragma unroll
  for (int jt = 0; jt < 8; ++jt) bias_r[jt] = bias[jt * 16 + r];

  int nrgTot = (N + 31) >> 5;
  int wStride = nbPart * 8;
  int wBase = bLoc * 8 + wave;
  int nrgW = (wBase < nrgTot) ? (nrgTot - wBase + wStride - 1) / wStride : 0;

  floatx4 acc[2][8];
#pragma unroll
  for (int t = 0; t < 2; ++t)
#pragma unroll
    for (int j = 0; j < 8; ++j) acc[t][j] = floatx4{0.f, 0.f, 0.f, 0.f};

  auto issueA = [&](int j, int m, bf16x8 (&buf)[2][4]) {
    if (j >= nrgW) return;  // wave-uniform
    int rowb = (wBase + j * wStride) << 5;
    const short* X = (m == 0) ? mV : (m == 1) ? mL : xb;
#pragma unroll
    for (int t = 0; t < 2; ++t) {
      int row = rowb + t * 16 + r;
      row = row < N ? row : N - 1;
      const short* Xr = X + (size_t)row * H + quad * 8;
#pragma unroll
      for (int kk = 0; kk < 4; ++kk) buf[t][kk] = *(const bf16x8*)(Xr + kk * 32);
    }
  };

  auto computeB = [&](int m, bf16x8 (&buf)[2][4]) {
    const short* Wm = Wlds + m * 16384;
#pragma unroll
    for (int kk = 0; kk < 4; ++kk) {
#pragma unroll
      for (int jt = 0; jt < 8; ++jt) {
        bf16x8 bfR = *(const bf16x8*)(Wm + (size_t)((jt * 4 + kk) * 64 + lane) * 8);
        acc[0][jt] = __builtin_amdgcn_mfma_f32_16x16x32_bf16(buf[0][kk], bfR, acc[0][jt], 0, 0, 0);
        acc[1][jt] = __builtin_amdgcn_mfma_f32_16x16x32_bf16(buf[1][kk], bfR, acc[1][jt], 0, 0, 0);
      }
    }
  };

  auto epi = [&](int j) {
    int rowb = (wBase + j * wStride) << 5;
#pragma unroll
    for (int t = 0; t < 2; ++t) {
#pragma unroll
      for (int jt = 0; jt < 8; ++jt) {
        int ocol = jt * 16 + r;
        float bv = bias_r[jt];
#pragma unroll
        for (int g = 0; g < 4; ++g) {
          int orow = rowb + t * 16 + quad * 4 + g;
          if (orow < N) {
            float v = acc[t][jt][g] + bv;
            if (relu) v = fmaxf(v, 0.f);
            if (out32) out32[(size_t)orow * H + ocol] = v;
            else       out16[(size_t)orow * H + ocol] = f2bf(v);
          }
        }
        acc[t][jt] = floatx4{0.f, 0.f, 0.f, 0.f};
      }
    }
  };

  bf16x8 A0[2][4], A1[2][4], A2[2][4];
  issueA(0, 0, A0);
  issueA(0, 1, A1);
  for (int j = 0; j < nrgW; ++j) {
    issueA(j, 2, A2);
    computeB(0, A0);
    issueA(j + 1, 0, A0);
    computeB(1, A1);
    issueA(j + 1, 1, A1);
    computeB(2, A2);
    epi(j);
  }
}

extern "C" void kernel_launch(void* const* d_in, const int* in_sizes, int n_in,
                              void* d_out, int out_size, void* d_ws, size_t ws_size,
                              hipStream_t stream) {
  const float* emb_user = (const float*)d_in[0];
  const float* emb_post = (const float*)d_in[1];
  const float* W_l = (const float*)d_in[2];
  const float* b_l = (const float*)d_in[3];
  const float* W_r = (const float*)d_in[4];
  const int* ev_s = (const int*)d_in[5];
  const int* ev_d = (const int*)d_in[6];
  const int* el_s = (const int*)d_in[7];
  const int* el_d = (const int*)d_in[8];

  const int NU = in_sizes[0] / H;
  const int NP = in_sizes[1] / H;
  const int EV = in_sizes[5];
  const int EL = in_sizes[7];
  const int T = 2 * NP + 2 * NU;
  const size_t NUH = (size_t)NU * H, NPH = (size_t)NP * H;

  // workspace carve (256B-aligned bumps)
  char* p = (char*)d_ws;
  auto alloc = [&](size_t bytes) -> void* {
    void* q = (void*)p; p += (bytes + 255) & ~(size_t)255; return q;
  };
  int*   cnt   = (int*)alloc((size_t)T * 4);
  int*   off   = (int*)alloc((size_t)T * 4);
  int*   bsums = (int*)alloc(4 * 256 * 4);
  int*   slotVp = (int*)alloc((size_t)EV * 4);
  int*   slotVu = (int*)alloc((size_t)EV * 4);
  int*   slotLp = (int*)alloc((size_t)EL * 4);
  int*   slotLu = (int*)alloc((size_t)EL * 4);
  int*   sV_p  = (int*)alloc((size_t)EV * 4);
  int*   sV_u  = (int*)alloc((size_t)EV * 4);
  int*   sL_p  = (int*)alloc((size_t)EL * 4);
  int*   sL_u  = (int*)alloc((size_t)EL * 4);
  short* Wbf   = (short*)alloc((size_t)4 * 3 * 16384 * 2);
  float* bc    = (float*)alloc(4 * H * 4);
  short* xbf_u  = (short*)alloc(NUH * 2);
  short* xbf_p  = (short*)alloc(NPH * 2);
  short* xbf1_u = (short*)alloc(NUH * 2);
  short* xbf1_p = (short*)alloc(NPH * 2);
  short* mVp    = (short*)alloc(NPH * 2);
  short* mLp    = (short*)alloc(NPH * 2);
  short* mVu    = (short*)alloc(NUH * 2);
  short* mLu    = (short*)alloc(NUH * 2);

  float* out_u_final = (float*)d_out;
  float* out_p_final = (float*)d_out + NUH;

  // count-array index order: {V_p:0, L_p:NP, V_u:2NP, L_u:2NP+NU}
  const int oV_p = 0, oL_p = NP, oV_u = 2 * NP, oL_u = 2 * NP + NU;

  hipMemsetAsync(cnt, 0, (size_t)T * 4, stream);

  // fused preprocessing A: count+slot (blocks first), cvt, prep
  int nbCnt = (EV + EL + 255) / 256;
  int nbCvt = ((int)((NUH + NPH) / 4) + 255) / 256;
  int nbPrep = (4 * 16384 + 255) / 256;
  preproc_a<<<nbCnt + nbCvt + nbPrep, 256, 0, stream>>>(
      ev_s, ev_d, EV, el_s, el_d, EL,
      cnt, oV_u, oV_p, oL_u, oL_p,
      slotVp, slotVu, slotLp, slotLu,
      emb_user, xbf_u, (int)NUH, emb_post, xbf_p, (int)NPH,
      W_l, b_l, W_r, Wbf, bc, nbCnt, nbCvt);

  int4 starts = { oV_p, oL_p, oV_u, oL_u };
  int4 lens   = { NP, NP, NU, NU };
  int maxb = ((NP > NU ? NP : NU) + 1023) / 1024;
  dim3 gscan(maxb, 4, 1);
  scan_k1<<<gscan, 256, 0, stream>>>(cnt, off, bsums, starts, lens);
  scan_k2<<<4, 256, 0, stream>>>(bsums, lens);
  scan_k3<<<gscan, 256, 0, stream>>>(off, bsums, starts, lens);

  fill_csr3<<<(EV + EL + 255) / 256, 256, 0, stream>>>(
      ev_s, ev_d, EV, el_s, el_d, EL, off,
      slotVp, slotVu, slotLp, slotLu,
      sV_p, sV_u, sL_p, sL_u, oV_p, oV_u, oL_p, oL_u);

  // 96 KB dynamic LDS for the fused GEMM
  const int ldsBytes = 3 * 16384 * 2;
  hipFuncSetAttribute((const void*)fused_gemm2, hipFuncAttributeMaxDynamicSharedMemorySize,
                      ldsBytes);

  // aggregate grid split (16 nodes per 256-thread block)
  int nbAggP = (NP + 15) / 16;
  int nbAggU = (NU + 15) / 16;

  // gemm grid: 256 blocks (1/CU, LDS-capped), split proportional to rows
  const int GB = 256;
  int nbP = (int)(((long long)GB * NP) / ((long long)NP + NU));
  if (nbP < 1) nbP = 1;
  if (nbP > GB - 1) nbP = GB - 1;

  for (int l = 0; l < 2; ++l) {
    const short* xu = l ? xbf1_u : xbf_u;
    const short* xp = l ? xbf1_p : xbf_p;
    const short* Wpost = Wbf + (size_t)(l * 2 + 0) * 3 * 16384;
    const short* Wuser = Wbf + (size_t)(l * 2 + 1) * 3 * 16384;
    const float* bpost = bc + (l * 2 + 0) * H;
    const float* buser = bc + (l * 2 + 1) * H;

    // both aggregations (posts from users, users from posts) in one launch
    aggregate2<<<nbAggP + nbAggU, 256, 0, stream>>>(
        (const bf16x8*)xu,
        sV_p, off + oV_p, cnt + oV_p,
        sL_p, off + oL_p, cnt + oL_p,
        (bf16x8*)mVp, (bf16x8*)mLp, NP, nbAggP,
        (const bf16x8*)xp,
        sV_u, off + oV_u, cnt + oV_u,
        sL_u, off + oL_u, cnt + oL_u,
        (bf16x8*)mVu, (bf16x8*)mLu, NU);

    // both transforms in one launch
    fused_gemm2<<<GB, 512, ldsBytes, stream>>>(
        mVp, mLp, xp, Wpost, bpost,
        l ? out_p_final : nullptr, l ? nullptr : xbf1_p, NP, nbP,
        mVu, mLu, xu, Wuser, buser,
        l ? out_u_final : nullptr, l ? nullptr : xbf1_u, NU, l == 0);
  }
}